// Round 3
// baseline (377.210 us; speedup 1.0000x reference)
//
#include <hip/hip_runtime.h>
#include <math.h>

// GCNII graph convolution, N=50000, F=256, E=800000, f32 in/out.
// R3: XCD feature-sliced gather -- slice s=bid%8 pinned to XCD s (round-robin
//     dispatch), per-XCD working set 3.2MB < 4MB L2; wave = 8 edge-groups x
//     8 feat-lanes for 8-16x MLP; shfl_xor reduce.
//     GEMM: 4-wave blocks, 128x128 tile.

#define F_DIM 256

typedef __attribute__((ext_vector_type(4))) float f32x4;
typedef __attribute__((ext_vector_type(8))) short short8;
typedef __attribute__((ext_vector_type(4))) unsigned short u16x4;

static __device__ __forceinline__ unsigned short f2bf(float f) {
    unsigned int u = __float_as_uint(f);
    u += 0x7fffu + ((u >> 16) & 1u);
    return (unsigned short)(u >> 16);
}
static __device__ __forceinline__ float bf2f(unsigned short u) {
    return __uint_as_float((unsigned int)u << 16);
}

// ---- CSR build ------------------------------------------------------------

__global__ void count_kernel(const int* __restrict__ src, const int* __restrict__ dst,
                             int* cnt_src, int* cnt_dst, int E) {
    int e = blockIdx.x * blockDim.x + threadIdx.x;
    if (e < E) {
        atomicAdd(&cnt_src[src[e]], 1);
        atomicAdd(&cnt_dst[dst[e]], 1);
    }
}

// single-block scan: thread owns a contiguous chunk; wave shfl-scan of sums.
__global__ __launch_bounds__(1024) void scan_kernel(const int* __restrict__ cnt,
                                                    int* __restrict__ row_ptr, int n) {
    __shared__ int wsum[16];
    int tid = threadIdx.x;
    int C = (n + 1023) / 1024;
    int beg = tid * C;
    int end = beg + C < n ? beg + C : n;
    int s = 0;
    for (int i = beg; i < end; ++i) s += cnt[i];
    int lane = tid & 63, wid = tid >> 6;
    int v = s;
    for (int off = 1; off < 64; off <<= 1) {
        int t = __shfl_up(v, off, 64);
        if (lane >= off) v += t;
    }
    if (lane == 63) wsum[wid] = v;
    __syncthreads();
    if (tid == 0) {
        int run = 0;
        for (int w = 0; w < 16; ++w) { int t = wsum[w]; wsum[w] = run; run += t; }
    }
    __syncthreads();
    int run = wsum[wid] + v - s;          // exclusive prefix for this chunk
    for (int i = beg; i < end; ++i) { row_ptr[i] = run; run += cnt[i]; }
    if (tid == 1023) row_ptr[n] = run;    // tid 1023's chunk is empty => run == total
}

__global__ void dinv_kernel(const int* __restrict__ cnt_dst,
                            float* __restrict__ dinv, int n) {
    int i = blockIdx.x * blockDim.x + threadIdx.x;
    if (i < n) dinv[i] = rsqrtf((float)cnt_dst[i] + 1.0f);
}

__global__ void fill_kernel(const int* __restrict__ src, const int* __restrict__ dst,
                            const int* __restrict__ row_ptr, int* cursor,
                            int* __restrict__ col, int E) {
    int e = blockIdx.x * blockDim.x + threadIdx.x;
    if (e < E) {
        int s = src[e];
        int pos = atomicAdd(&cursor[s], 1);
        col[row_ptr[s] + pos] = dst[e];
    }
}

// ---- Hs = bf16(H * dinv[row]) ---------------------------------------------

__global__ __launch_bounds__(256) void hs_kernel(const float* __restrict__ H,
                                                 const float* __restrict__ dinv,
                                                 unsigned short* __restrict__ Hs,
                                                 int total4) {
    int i = blockIdx.x * 256 + threadIdx.x;   // index in f32x4 / u16x4 units
    if (i >= total4) return;
    int row = i >> 6;                          // 64 x f32x4 per row
    float d = dinv[row];
    f32x4 x = ((const f32x4*)H)[i];
    u16x4 o;
    o[0] = f2bf(x[0] * d); o[1] = f2bf(x[1] * d);
    o[2] = f2bf(x[2] * d); o[3] = f2bf(x[3] * d);
    ((u16x4*)Hs)[i] = o;
}

// ---- W transpose to bf16 (Wt[n][k]) ---------------------------------------

__global__ void wt_kernel(const float* __restrict__ W, unsigned short* __restrict__ Wt) {
    int n = blockIdx.x;
    int k = threadIdx.x;
    Wt[n * F_DIM + k] = f2bf(W[k * F_DIM + n]);
}

// ---- gather: XCD feature-sliced, 8 edges/wave-step, shfl reduce -----------
// Persistent grid of NB blocks; slice = bid % 8 (binds to one XCD under
// round-robin dispatch); per-XCD Hs working set = 25.6MB/8 = 3.2MB < 4MB L2.
// Wave handles one row-slice: lane = eg*8 + fl; eg = edge group (8 edges in
// parallel), fl = feat sub-lane (u16x4 = 8B -> 8 lanes x 8B = 64B slice).

#define GATHER_NB 2048

__global__ __launch_bounds__(256) void gather_kernel(
        const unsigned short* __restrict__ Hs, const float* __restrict__ H0,
        const int* __restrict__ row_ptr, const int* __restrict__ col,
        const float* __restrict__ dinv, const float* __restrict__ alpha_p,
        unsigned short* __restrict__ irb, int n) {
    int wave = threadIdx.x >> 6;
    int lane = threadIdx.x & 63;
    int fl = lane & 7;          // feature sub-lane
    int eg = lane >> 3;         // edge group
    int slice = blockIdx.x & 7;
    int g0 = blockIdx.x >> 3;   // 0..255
    int ngrp = (n + 3) >> 2;
    float alpha = alpha_p[0];
    const u16x4* Hs4 = (const u16x4*)Hs;
    int sb = slice * 8 + fl;    // u16x4 index within a row

    for (int g = g0; g < ngrp; g += GATHER_NB / 8) {
        int row = g * 4 + wave;
        if (row >= n) continue;
        f32x4 acc = 0.0f;
        int beg = row_ptr[row], end = row_ptr[row + 1];
        int e0 = beg;
        for (; e0 + 16 <= end; e0 += 16) {         // 16 edges in flight
            int ja = col[e0 + eg];
            int jb = col[e0 + 8 + eg];
            u16x4 ha = Hs4[ja * 64 + sb];
            u16x4 hb = Hs4[jb * 64 + sb];
            acc[0] += bf2f(ha[0]) + bf2f(hb[0]);
            acc[1] += bf2f(ha[1]) + bf2f(hb[1]);
            acc[2] += bf2f(ha[2]) + bf2f(hb[2]);
            acc[3] += bf2f(ha[3]) + bf2f(hb[3]);
        }
        for (; e0 < end; e0 += 8) {                // tail, predicated
            int e = e0 + eg;
            if (e < end) {
                int j = col[e];
                u16x4 h = Hs4[j * 64 + sb];
                acc[0] += bf2f(h[0]); acc[1] += bf2f(h[1]);
                acc[2] += bf2f(h[2]); acc[3] += bf2f(h[3]);
            }
        }
        // reduce across the 8 edge groups (xor lane bits 3..5)
        for (int d = 8; d < 64; d <<= 1) {
            acc[0] += __shfl_xor(acc[0], d);
            acc[1] += __shfl_xor(acc[1], d);
            acc[2] += __shfl_xor(acc[2], d);
            acc[3] += __shfl_xor(acc[3], d);
        }
        if (eg == 0) {
            // self loop: H/deg = Hs * dinv  =>  PH = dinv[row]*(acc + Hs_row)
            u16x4 hr = Hs4[row * 64 + sb];
            acc[0] += bf2f(hr[0]); acc[1] += bf2f(hr[1]);
            acc[2] += bf2f(hr[2]); acc[3] += bf2f(hr[3]);
            float di = dinv[row];
            f32x4 h0 = ((const f32x4*)H0)[row * 64 + sb];
            f32x4 init = (1.0f - alpha) * (di * acc) + alpha * h0;
            u16x4 o;
            o[0] = f2bf(init[0]); o[1] = f2bf(init[1]);
            o[2] = f2bf(init[2]); o[3] = f2bf(init[3]);
            ((u16x4*)irb)[row * 64 + sb] = o;
        }
    }
}

// ---- GEMM: out = (1-beta)*irb + beta*(irb @ W), bf16 MFMA 16x16x32 --------
// 4 waves/block, block tile 128 rows x 128 cols; wave tile 64x64; K=256.

__global__ __launch_bounds__(256) void gemm_kernel(
        const unsigned short* __restrict__ irb, const unsigned short* __restrict__ Wt,
        float* __restrict__ out, const float* __restrict__ lamda_p,
        const int* __restrict__ l_p, int M) {
    int w = threadIdx.x >> 6;
    int mr = blockIdx.x * 128 + (w >> 1) * 64;
    int nc = blockIdx.y * 128 + (w & 1) * 64;
    int lane = threadIdx.x & 63;
    int lo = lane & 15, hi = lane >> 4;
    float beta = logf(lamda_p[0] / (float)l_p[0] + 1.0f);
    float ob = 1.0f - beta;

    f32x4 acc[4][4] = {};
    for (int kk = 0; kk < 8; ++kk) {
        int kb = kk * 32 + hi * 8;
        short8 a[4], b[4];
        for (int am = 0; am < 4; ++am) {
            int row = mr + am * 16 + lo;
            a[am] = (row < M) ? *(const short8*)(irb + (size_t)row * F_DIM + kb)
                              : (short8)0;
        }
        for (int bn = 0; bn < 4; ++bn) {
            int cb = nc + bn * 16 + lo;
            b[bn] = *(const short8*)(Wt + cb * F_DIM + kb);
        }
        for (int am = 0; am < 4; ++am)
            for (int bn = 0; bn < 4; ++bn)
                acc[am][bn] = __builtin_amdgcn_mfma_f32_16x16x32_bf16(
                    a[am], b[bn], acc[am][bn], 0, 0, 0);
    }

    // C/D layout: col = lane&15, row = (lane>>4)*4 + reg   [m89-verified]
    for (int am = 0; am < 4; ++am) {
        int rbase = mr + am * 16 + hi * 4;
        for (int r = 0; r < 4; ++r) {
            int row = rbase + r;
            if (row >= M) continue;
            for (int bn = 0; bn < 4; ++bn) {
                int c2 = nc + bn * 16 + lo;
                size_t idx = (size_t)row * F_DIM + c2;
                out[idx] = ob * bf2f(irb[idx]) + beta * acc[am][bn][r];
            }
        }
    }
}

// ---- launch ---------------------------------------------------------------

extern "C" void kernel_launch(void* const* d_in, const int* in_sizes, int n_in,
                              void* d_out, int out_size, void* d_ws, size_t ws_size,
                              hipStream_t stream) {
    const float* H     = (const float*)d_in[0];
    const int*   ei    = (const int*)d_in[1];
    const float* H0    = (const float*)d_in[2];
    const float* W     = (const float*)d_in[3];
    const float* lamda = (const float*)d_in[4];
    const float* alpha = (const float*)d_in[5];
    const int*   lp    = (const int*)d_in[6];

    int n = in_sizes[0] / F_DIM;
    int E = in_sizes[1] / 2;
    const int* src = ei;
    const int* dst = ei + E;
    float* out = (float*)d_out;

    char* ws = (char*)d_ws;
    size_t off = 0;
    auto alloc = [&](size_t bytes) -> void* {
        void* p = ws + off;
        off += (bytes + 255) & ~(size_t)255;
        return p;
    };
    int* cnt_src = (int*)alloc((size_t)n * 4);
    int* cnt_dst = (int*)alloc((size_t)n * 4);
    int* cursor  = (int*)alloc((size_t)n * 4);
    int* row_ptr = (int*)alloc(((size_t)n + 1) * 4);
    float* dinv  = (float*)alloc((size_t)n * 4);
    int* colb    = (int*)alloc((size_t)E * 4);
    unsigned short* Wt  = (unsigned short*)alloc((size_t)F_DIM * F_DIM * 2);
    unsigned short* Hs  = (unsigned short*)alloc((size_t)n * F_DIM * 2);
    unsigned short* irb = (unsigned short*)alloc(((size_t)n + 128) * F_DIM * 2);

    // zero count/cursor arrays (contiguous region up to row_ptr)
    hipMemsetAsync(cnt_src, 0, (char*)row_ptr - (char*)cnt_src, stream);

    count_kernel<<<(E + 255) / 256, 256, 0, stream>>>(src, dst, cnt_src, cnt_dst, E);
    scan_kernel<<<1, 1024, 0, stream>>>(cnt_src, row_ptr, n);
    dinv_kernel<<<(n + 255) / 256, 256, 0, stream>>>(cnt_dst, dinv, n);
    fill_kernel<<<(E + 255) / 256, 256, 0, stream>>>(src, dst, row_ptr, cursor, colb, E);
    hs_kernel<<<(n * 64 + 255) / 256, 256, 0, stream>>>(H, dinv, Hs, n * 64);
    wt_kernel<<<F_DIM, F_DIM, 0, stream>>>(W, Wt);
    gather_kernel<<<GATHER_NB, 256, 0, stream>>>(Hs, H0, row_ptr, colb, dinv,
                                                 alpha, irb, n);
    int mtiles = (n + 127) / 128;
    dim3 ggrid(mtiles, 2);
    gemm_kernel<<<ggrid, 256, 0, stream>>>(irb, Wt, out, lamda, lp, n);
}

// Round 4
// 364.666 us; speedup vs baseline: 1.0344x; 1.0344x over previous
//
#include <hip/hip_runtime.h>
#include <math.h>

// GCNII graph convolution, N=50000, F=256, E=800000, f32 in/out.
// R4: revert gather to wave-per-row 512B loads (R2) + 8-deep edge unroll with
//     independent accumulators (raise MLP: latency-bound at ~1 load/wave in
//     R2). count_kernel records rank[e] so fill needs no atomics; dinv fused
//     into scan kernel.

#define F_DIM 256

typedef __attribute__((ext_vector_type(4))) float f32x4;
typedef __attribute__((ext_vector_type(8))) short short8;
typedef __attribute__((ext_vector_type(4))) unsigned short u16x4;

static __device__ __forceinline__ unsigned short f2bf(float f) {
    unsigned int u = __float_as_uint(f);
    u += 0x7fffu + ((u >> 16) & 1u);
    return (unsigned short)(u >> 16);
}
static __device__ __forceinline__ float bf2f(unsigned short u) {
    return __uint_as_float((unsigned int)u << 16);
}

// ---- CSR build ------------------------------------------------------------

__global__ void count_kernel(const int* __restrict__ src, const int* __restrict__ dst,
                             int* cnt_src, int* cnt_dst, int* __restrict__ rank, int E) {
    int e = blockIdx.x * blockDim.x + threadIdx.x;
    if (e < E) {
        rank[e] = atomicAdd(&cnt_src[src[e]], 1);
        atomicAdd(&cnt_dst[dst[e]], 1);
    }
}

// single-block scan over cnt_src -> row_ptr; also computes dinv from cnt_dst.
__global__ __launch_bounds__(1024) void scan_kernel(const int* __restrict__ cnt,
                                                    const int* __restrict__ cnt_dst,
                                                    int* __restrict__ row_ptr,
                                                    float* __restrict__ dinv, int n) {
    __shared__ int wsum[16];
    int tid = threadIdx.x;
    int C = (n + 1023) / 1024;
    int beg = tid * C;
    int end = beg + C < n ? beg + C : n;
    int s = 0;
    for (int i = beg; i < end; ++i) s += cnt[i];
    int lane = tid & 63, wid = tid >> 6;
    int v = s;
    for (int off = 1; off < 64; off <<= 1) {
        int t = __shfl_up(v, off, 64);
        if (lane >= off) v += t;
    }
    if (lane == 63) wsum[wid] = v;
    __syncthreads();
    if (tid == 0) {
        int run = 0;
        for (int w = 0; w < 16; ++w) { int t = wsum[w]; wsum[w] = run; run += t; }
    }
    __syncthreads();
    int run = wsum[wid] + v - s;          // exclusive prefix for this chunk
    for (int i = beg; i < end; ++i) { row_ptr[i] = run; run += cnt[i]; }
    if (tid == 1023) row_ptr[n] = run;    // tid 1023's chunk is empty => run == total
    for (int i = beg; i < end; ++i) dinv[i] = rsqrtf((float)cnt_dst[i] + 1.0f);
}

__global__ void fill_kernel(const int* __restrict__ src, const int* __restrict__ dst,
                            const int* __restrict__ row_ptr, const int* __restrict__ rank,
                            int* __restrict__ col, int E) {
    int e = blockIdx.x * blockDim.x + threadIdx.x;
    if (e < E) col[row_ptr[src[e]] + rank[e]] = dst[e];
}

// ---- Hs = bf16(H * dinv[row]) ---------------------------------------------

__global__ __launch_bounds__(256) void hs_kernel(const float* __restrict__ H,
                                                 const float* __restrict__ dinv,
                                                 unsigned short* __restrict__ Hs,
                                                 int total4) {
    int i = blockIdx.x * 256 + threadIdx.x;   // index in f32x4 / u16x4 units
    if (i >= total4) return;
    int row = i >> 6;                          // 64 x f32x4 per row
    float d = dinv[row];
    f32x4 x = ((const f32x4*)H)[i];
    u16x4 o;
    o[0] = f2bf(x[0] * d); o[1] = f2bf(x[1] * d);
    o[2] = f2bf(x[2] * d); o[3] = f2bf(x[3] * d);
    ((u16x4*)Hs)[i] = o;
}

// ---- W transpose to bf16 (Wt[n][k]) ---------------------------------------

__global__ void wt_kernel(const float* __restrict__ W, unsigned short* __restrict__ Wt) {
    int n = blockIdx.x;
    int k = threadIdx.x;
    Wt[n * F_DIM + k] = f2bf(W[k * F_DIM + n]);
}

// ---- gather: one wave per row, 512B coalesced loads, 8-deep edge unroll ----

#define ACC(A, h) { A[0] += bf2f(h[0]); A[1] += bf2f(h[1]); \
                    A[2] += bf2f(h[2]); A[3] += bf2f(h[3]); }

__global__ __launch_bounds__(256) void gather_kernel(
        const unsigned short* __restrict__ Hs, const float* __restrict__ H0,
        const int* __restrict__ row_ptr, const int* __restrict__ col,
        const float* __restrict__ dinv, const float* __restrict__ alpha_p,
        unsigned short* __restrict__ irb, int n) {
    int wave = threadIdx.x >> 6;
    int lane = threadIdx.x & 63;
    int row = blockIdx.x * 4 + wave;
    if (row >= n) return;
    float alpha = alpha_p[0];
    const u16x4* Hs4 = (const u16x4*)Hs;

    int beg = row_ptr[row], end = row_ptr[row + 1];
    f32x4 a0 = 0.0f, a1 = 0.0f, a2 = 0.0f, a3 = 0.0f;
    int e = beg;
    for (; e + 8 <= end; e += 8) {             // 8 gathers in flight
        int j0 = col[e+0], j1 = col[e+1], j2 = col[e+2], j3 = col[e+3];
        int j4 = col[e+4], j5 = col[e+5], j6 = col[e+6], j7 = col[e+7];
        u16x4 h0 = Hs4[j0*64+lane], h1 = Hs4[j1*64+lane];
        u16x4 h2 = Hs4[j2*64+lane], h3 = Hs4[j3*64+lane];
        u16x4 h4 = Hs4[j4*64+lane], h5 = Hs4[j5*64+lane];
        u16x4 h6 = Hs4[j6*64+lane], h7 = Hs4[j7*64+lane];
        ACC(a0, h0) ACC(a1, h1) ACC(a2, h2) ACC(a3, h3)
        ACC(a0, h4) ACC(a1, h5) ACC(a2, h6) ACC(a3, h7)
    }
    for (; e + 4 <= end; e += 4) {
        int j0 = col[e+0], j1 = col[e+1], j2 = col[e+2], j3 = col[e+3];
        u16x4 h0 = Hs4[j0*64+lane], h1 = Hs4[j1*64+lane];
        u16x4 h2 = Hs4[j2*64+lane], h3 = Hs4[j3*64+lane];
        ACC(a0, h0) ACC(a1, h1) ACC(a2, h2) ACC(a3, h3)
    }
    for (; e < end; ++e) {
        int j = col[e];
        u16x4 h = Hs4[j*64+lane];
        ACC(a0, h)
    }
    // self loop: H/deg = Hs * dinv  =>  PH = dinv[row] * (sum + Hs_row)
    u16x4 hr = Hs4[row*64+lane];
    ACC(a2, hr)
    f32x4 acc = (a0 + a1) + (a2 + a3);
    float di = dinv[row];
    f32x4 h0v = ((const f32x4*)H0)[row * 64 + lane];
    f32x4 init = (1.0f - alpha) * (di * acc) + alpha * h0v;
    u16x4 o;
    o[0] = f2bf(init[0]); o[1] = f2bf(init[1]);
    o[2] = f2bf(init[2]); o[3] = f2bf(init[3]);
    ((u16x4*)irb)[row * 64 + lane] = o;
}

// ---- GEMM: out = (1-beta)*irb + beta*(irb @ W), bf16 MFMA 16x16x32 --------
// 4 waves/block, block tile 128 rows x 128 cols; wave tile 64x64; K=256.

__global__ __launch_bounds__(256) void gemm_kernel(
        const unsigned short* __restrict__ irb, const unsigned short* __restrict__ Wt,
        float* __restrict__ out, const float* __restrict__ lamda_p,
        const int* __restrict__ l_p, int M) {
    int w = threadIdx.x >> 6;
    int mr = blockIdx.x * 128 + (w >> 1) * 64;
    int nc = blockIdx.y * 128 + (w & 1) * 64;
    int lane = threadIdx.x & 63;
    int lo = lane & 15, hi = lane >> 4;
    float beta = logf(lamda_p[0] / (float)l_p[0] + 1.0f);
    float ob = 1.0f - beta;

    f32x4 acc[4][4] = {};
    for (int kk = 0; kk < 8; ++kk) {
        int kb = kk * 32 + hi * 8;
        short8 a[4], b[4];
        for (int am = 0; am < 4; ++am) {
            int row = mr + am * 16 + lo;
            a[am] = (row < M) ? *(const short8*)(irb + (size_t)row * F_DIM + kb)
                              : (short8)0;
        }
        for (int bn = 0; bn < 4; ++bn) {
            int cb = nc + bn * 16 + lo;
            b[bn] = *(const short8*)(Wt + cb * F_DIM + kb);
        }
        for (int am = 0; am < 4; ++am)
            for (int bn = 0; bn < 4; ++bn)
                acc[am][bn] = __builtin_amdgcn_mfma_f32_16x16x32_bf16(
                    a[am], b[bn], acc[am][bn], 0, 0, 0);
    }

    // C/D layout: col = lane&15, row = (lane>>4)*4 + reg   [m89-verified]
    for (int am = 0; am < 4; ++am) {
        int rbase = mr + am * 16 + hi * 4;
        for (int r = 0; r < 4; ++r) {
            int row = rbase + r;
            if (row >= M) continue;
            for (int bn = 0; bn < 4; ++bn) {
                int c2 = nc + bn * 16 + lo;
                size_t idx = (size_t)row * F_DIM + c2;
                out[idx] = ob * bf2f(irb[idx]) + beta * acc[am][bn][r];
            }
        }
    }
}

// ---- launch ---------------------------------------------------------------

extern "C" void kernel_launch(void* const* d_in, const int* in_sizes, int n_in,
                              void* d_out, int out_size, void* d_ws, size_t ws_size,
                              hipStream_t stream) {
    const float* H     = (const float*)d_in[0];
    const int*   ei    = (const int*)d_in[1];
    const float* H0    = (const float*)d_in[2];
    const float* W     = (const float*)d_in[3];
    const float* lamda = (const float*)d_in[4];
    const float* alpha = (const float*)d_in[5];
    const int*   lp    = (const int*)d_in[6];

    int n = in_sizes[0] / F_DIM;
    int E = in_sizes[1] / 2;
    const int* src = ei;
    const int* dst = ei + E;
    float* out = (float*)d_out;

    char* ws = (char*)d_ws;
    size_t off = 0;
    auto alloc = [&](size_t bytes) -> void* {
        void* p = ws + off;
        off += (bytes + 255) & ~(size_t)255;
        return p;
    };
    int* cnt_src = (int*)alloc((size_t)n * 4);
    int* cnt_dst = (int*)alloc((size_t)n * 4);
    int* row_ptr = (int*)alloc(((size_t)n + 1) * 4);
    float* dinv  = (float*)alloc((size_t)n * 4);
    int* rank    = (int*)alloc((size_t)E * 4);
    int* colb    = (int*)alloc((size_t)E * 4);
    unsigned short* Wt  = (unsigned short*)alloc((size_t)F_DIM * F_DIM * 2);
    unsigned short* Hs  = (unsigned short*)alloc((size_t)n * F_DIM * 2);
    unsigned short* irb = (unsigned short*)alloc(((size_t)n + 128) * F_DIM * 2);

    // zero the two count arrays (contiguous region up to row_ptr)
    hipMemsetAsync(cnt_src, 0, (char*)row_ptr - (char*)cnt_src, stream);

    count_kernel<<<(E + 255) / 256, 256, 0, stream>>>(src, dst, cnt_src, cnt_dst, rank, E);
    scan_kernel<<<1, 1024, 0, stream>>>(cnt_src, cnt_dst, row_ptr, dinv, n);
    fill_kernel<<<(E + 255) / 256, 256, 0, stream>>>(src, dst, row_ptr, rank, colb, E);
    hs_kernel<<<(n * 64 + 255) / 256, 256, 0, stream>>>(H, dinv, Hs, n * 64);
    wt_kernel<<<F_DIM, F_DIM, 0, stream>>>(W, Wt);
    gather_kernel<<<(n + 3) / 4, 256, 0, stream>>>(Hs, H0, row_ptr, colb, dinv,
                                                   alpha, irb, n);
    int mtiles = (n + 127) / 128;
    dim3 ggrid(mtiles, 2);
    gemm_kernel<<<ggrid, 256, 0, stream>>>(irb, Wt, out, lamda, lp, n);
}

// Round 5
// 224.241 us; speedup vs baseline: 1.6822x; 1.6262x over previous
//
#include <hip/hip_runtime.h>
#include <math.h>

// GCNII graph convolution, N=50000, F=256, E=800000, f32 in/out.
// R5: hierarchical coalesced scan (blocksum -> scan sums -> local scan+offset)
//     replacing the 154us single-block scan; dinv back to its own coalesced
//     kernel. Gather (8-deep unroll) and GEMM (128x128, 4-wave) unchanged.

#define F_DIM 256

typedef __attribute__((ext_vector_type(4))) float f32x4;
typedef __attribute__((ext_vector_type(8))) short short8;
typedef __attribute__((ext_vector_type(4))) unsigned short u16x4;

static __device__ __forceinline__ unsigned short f2bf(float f) {
    unsigned int u = __float_as_uint(f);
    u += 0x7fffu + ((u >> 16) & 1u);
    return (unsigned short)(u >> 16);
}
static __device__ __forceinline__ float bf2f(unsigned short u) {
    return __uint_as_float((unsigned int)u << 16);
}

// ---- CSR build ------------------------------------------------------------

__global__ void count_kernel(const int* __restrict__ src, const int* __restrict__ dst,
                             int* cnt_src, int* cnt_dst, int* __restrict__ rank, int E) {
    int e = blockIdx.x * blockDim.x + threadIdx.x;
    if (e < E) {
        rank[e] = atomicAdd(&cnt_src[src[e]], 1);
        atomicAdd(&cnt_dst[dst[e]], 1);
    }
}

// Phase A: per-block sum of 256 counts (coalesced).
__global__ __launch_bounds__(256) void blksum_kernel(const int* __restrict__ cnt,
                                                     int* __restrict__ blksum, int n) {
    int i = blockIdx.x * 256 + threadIdx.x;
    int v = (i < n) ? cnt[i] : 0;
    int lane = threadIdx.x & 63, w = threadIdx.x >> 6;
    for (int off = 32; off > 0; off >>= 1) v += __shfl_down(v, off, 64);
    __shared__ int ws[4];
    if (lane == 0) ws[w] = v;
    __syncthreads();
    if (threadIdx.x == 0)
        blksum[blockIdx.x] = ws[0] + ws[1] + ws[2] + ws[3];
}

// Phase B: exclusive scan of nb (<=256) block sums, single block.
__global__ __launch_bounds__(256) void blkscan_kernel(const int* __restrict__ blksum,
                                                      int* __restrict__ blkoff, int nb) {
    int tid = threadIdx.x;
    int v = (tid < nb) ? blksum[tid] : 0;
    int s = v;
    int lane = tid & 63, w = tid >> 6;
    for (int off = 1; off < 64; off <<= 1) {
        int t = __shfl_up(v, off, 64);
        if (lane >= off) v += t;
    }
    __shared__ int ws[4];
    if (lane == 63) ws[w] = v;
    __syncthreads();
    if (tid == 0) {
        int run = 0;
        for (int i = 0; i < 4; ++i) { int t = ws[i]; ws[i] = run; run += t; }
    }
    __syncthreads();
    if (tid < nb) blkoff[tid] = ws[w] + v - s;   // exclusive
}

// Phase C: local exclusive scan + block offset -> row_ptr (coalesced).
// Covers indices 0..n inclusive (row_ptr[n] = total).
__global__ __launch_bounds__(256) void rowptr_kernel(const int* __restrict__ cnt,
                                                     const int* __restrict__ blkoff,
                                                     int* __restrict__ row_ptr, int n) {
    int i = blockIdx.x * 256 + threadIdx.x;
    int tid = threadIdx.x;
    int s = (i < n) ? cnt[i] : 0;
    int v = s;
    int lane = tid & 63, w = tid >> 6;
    for (int off = 1; off < 64; off <<= 1) {
        int t = __shfl_up(v, off, 64);
        if (lane >= off) v += t;
    }
    __shared__ int ws[4];
    if (lane == 63) ws[w] = v;
    __syncthreads();
    if (tid == 0) {
        int run = 0;
        for (int k = 0; k < 4; ++k) { int t = ws[k]; ws[k] = run; run += t; }
    }
    __syncthreads();
    if (i <= n) row_ptr[i] = blkoff[blockIdx.x] + ws[w] + v - s;
}

__global__ void dinv_kernel(const int* __restrict__ cnt_dst,
                            float* __restrict__ dinv, int n) {
    int i = blockIdx.x * blockDim.x + threadIdx.x;
    if (i < n) dinv[i] = rsqrtf((float)cnt_dst[i] + 1.0f);
}

__global__ void fill_kernel(const int* __restrict__ src, const int* __restrict__ dst,
                            const int* __restrict__ row_ptr, const int* __restrict__ rank,
                            int* __restrict__ col, int E) {
    int e = blockIdx.x * blockDim.x + threadIdx.x;
    if (e < E) col[row_ptr[src[e]] + rank[e]] = dst[e];
}

// ---- Hs = bf16(H * dinv[row]) ---------------------------------------------

__global__ __launch_bounds__(256) void hs_kernel(const float* __restrict__ H,
                                                 const float* __restrict__ dinv,
                                                 unsigned short* __restrict__ Hs,
                                                 int total4) {
    int i = blockIdx.x * 256 + threadIdx.x;   // index in f32x4 / u16x4 units
    if (i >= total4) return;
    int row = i >> 6;                          // 64 x f32x4 per row
    float d = dinv[row];
    f32x4 x = ((const f32x4*)H)[i];
    u16x4 o;
    o[0] = f2bf(x[0] * d); o[1] = f2bf(x[1] * d);
    o[2] = f2bf(x[2] * d); o[3] = f2bf(x[3] * d);
    ((u16x4*)Hs)[i] = o;
}

// ---- W transpose to bf16 (Wt[n][k]) ---------------------------------------

__global__ void wt_kernel(const float* __restrict__ W, unsigned short* __restrict__ Wt) {
    int n = blockIdx.x;
    int k = threadIdx.x;
    Wt[n * F_DIM + k] = f2bf(W[k * F_DIM + n]);
}

// ---- gather: one wave per row, 512B coalesced loads, 8-deep edge unroll ----

#define ACC(A, h) { A[0] += bf2f(h[0]); A[1] += bf2f(h[1]); \
                    A[2] += bf2f(h[2]); A[3] += bf2f(h[3]); }

__global__ __launch_bounds__(256) void gather_kernel(
        const unsigned short* __restrict__ Hs, const float* __restrict__ H0,
        const int* __restrict__ row_ptr, const int* __restrict__ col,
        const float* __restrict__ dinv, const float* __restrict__ alpha_p,
        unsigned short* __restrict__ irb, int n) {
    int wave = threadIdx.x >> 6;
    int lane = threadIdx.x & 63;
    int row = blockIdx.x * 4 + wave;
    if (row >= n) return;
    float alpha = alpha_p[0];
    const u16x4* Hs4 = (const u16x4*)Hs;

    int beg = row_ptr[row], end = row_ptr[row + 1];
    f32x4 a0 = 0.0f, a1 = 0.0f, a2 = 0.0f, a3 = 0.0f;
    int e = beg;
    for (; e + 8 <= end; e += 8) {             // 8 gathers in flight
        int j0 = col[e+0], j1 = col[e+1], j2 = col[e+2], j3 = col[e+3];
        int j4 = col[e+4], j5 = col[e+5], j6 = col[e+6], j7 = col[e+7];
        u16x4 h0 = Hs4[j0*64+lane], h1 = Hs4[j1*64+lane];
        u16x4 h2 = Hs4[j2*64+lane], h3 = Hs4[j3*64+lane];
        u16x4 h4 = Hs4[j4*64+lane], h5 = Hs4[j5*64+lane];
        u16x4 h6 = Hs4[j6*64+lane], h7 = Hs4[j7*64+lane];
        ACC(a0, h0) ACC(a1, h1) ACC(a2, h2) ACC(a3, h3)
        ACC(a0, h4) ACC(a1, h5) ACC(a2, h6) ACC(a3, h7)
    }
    for (; e + 4 <= end; e += 4) {
        int j0 = col[e+0], j1 = col[e+1], j2 = col[e+2], j3 = col[e+3];
        u16x4 h0 = Hs4[j0*64+lane], h1 = Hs4[j1*64+lane];
        u16x4 h2 = Hs4[j2*64+lane], h3 = Hs4[j3*64+lane];
        ACC(a0, h0) ACC(a1, h1) ACC(a2, h2) ACC(a3, h3)
    }
    for (; e < end; ++e) {
        int j = col[e];
        u16x4 h = Hs4[j*64+lane];
        ACC(a0, h)
    }
    // self loop: H/deg = Hs * dinv  =>  PH = dinv[row] * (sum + Hs_row)
    u16x4 hr = Hs4[row*64+lane];
    ACC(a2, hr)
    f32x4 acc = (a0 + a1) + (a2 + a3);
    float di = dinv[row];
    f32x4 h0v = ((const f32x4*)H0)[row * 64 + lane];
    f32x4 init = (1.0f - alpha) * (di * acc) + alpha * h0v;
    u16x4 o;
    o[0] = f2bf(init[0]); o[1] = f2bf(init[1]);
    o[2] = f2bf(init[2]); o[3] = f2bf(init[3]);
    ((u16x4*)irb)[row * 64 + lane] = o;
}

// ---- GEMM: out = (1-beta)*irb + beta*(irb @ W), bf16 MFMA 16x16x32 --------
// 4 waves/block, block tile 128 rows x 128 cols; wave tile 64x64; K=256.

__global__ __launch_bounds__(256) void gemm_kernel(
        const unsigned short* __restrict__ irb, const unsigned short* __restrict__ Wt,
        float* __restrict__ out, const float* __restrict__ lamda_p,
        const int* __restrict__ l_p, int M) {
    int w = threadIdx.x >> 6;
    int mr = blockIdx.x * 128 + (w >> 1) * 64;
    int nc = blockIdx.y * 128 + (w & 1) * 64;
    int lane = threadIdx.x & 63;
    int lo = lane & 15, hi = lane >> 4;
    float beta = logf(lamda_p[0] / (float)l_p[0] + 1.0f);
    float ob = 1.0f - beta;

    f32x4 acc[4][4] = {};
    for (int kk = 0; kk < 8; ++kk) {
        int kb = kk * 32 + hi * 8;
        short8 a[4], b[4];
        for (int am = 0; am < 4; ++am) {
            int row = mr + am * 16 + lo;
            a[am] = (row < M) ? *(const short8*)(irb + (size_t)row * F_DIM + kb)
                              : (short8)0;
        }
        for (int bn = 0; bn < 4; ++bn) {
            int cb = nc + bn * 16 + lo;
            b[bn] = *(const short8*)(Wt + cb * F_DIM + kb);
        }
        for (int am = 0; am < 4; ++am)
            for (int bn = 0; bn < 4; ++bn)
                acc[am][bn] = __builtin_amdgcn_mfma_f32_16x16x32_bf16(
                    a[am], b[bn], acc[am][bn], 0, 0, 0);
    }

    // C/D layout: col = lane&15, row = (lane>>4)*4 + reg   [m89-verified]
    for (int am = 0; am < 4; ++am) {
        int rbase = mr + am * 16 + hi * 4;
        for (int r = 0; r < 4; ++r) {
            int row = rbase + r;
            if (row >= M) continue;
            for (int bn = 0; bn < 4; ++bn) {
                int c2 = nc + bn * 16 + lo;
                size_t idx = (size_t)row * F_DIM + c2;
                out[idx] = ob * bf2f(irb[idx]) + beta * acc[am][bn][r];
            }
        }
    }
}

// ---- launch ---------------------------------------------------------------

extern "C" void kernel_launch(void* const* d_in, const int* in_sizes, int n_in,
                              void* d_out, int out_size, void* d_ws, size_t ws_size,
                              hipStream_t stream) {
    const float* H     = (const float*)d_in[0];
    const int*   ei    = (const int*)d_in[1];
    const float* H0    = (const float*)d_in[2];
    const float* W     = (const float*)d_in[3];
    const float* lamda = (const float*)d_in[4];
    const float* alpha = (const float*)d_in[5];
    const int*   lp    = (const int*)d_in[6];

    int n = in_sizes[0] / F_DIM;
    int E = in_sizes[1] / 2;
    const int* src = ei;
    const int* dst = ei + E;
    float* out = (float*)d_out;

    int nb = (n + 256) / 256;   // blocks covering 0..n inclusive (196 for n=50000)

    char* ws = (char*)d_ws;
    size_t off = 0;
    auto alloc = [&](size_t bytes) -> void* {
        void* p = ws + off;
        off += (bytes + 255) & ~(size_t)255;
        return p;
    };
    int* cnt_src = (int*)alloc((size_t)n * 4);
    int* cnt_dst = (int*)alloc((size_t)n * 4);
    int* row_ptr = (int*)alloc(((size_t)n + 1) * 4);
    int* blksum  = (int*)alloc((size_t)nb * 4);
    int* blkoff  = (int*)alloc((size_t)nb * 4);
    float* dinv  = (float*)alloc((size_t)n * 4);
    int* rank    = (int*)alloc((size_t)E * 4);
    int* colb    = (int*)alloc((size_t)E * 4);
    unsigned short* Wt  = (unsigned short*)alloc((size_t)F_DIM * F_DIM * 2);
    unsigned short* Hs  = (unsigned short*)alloc((size_t)n * F_DIM * 2);
    unsigned short* irb = (unsigned short*)alloc(((size_t)n + 128) * F_DIM * 2);

    // zero the two count arrays (contiguous region up to row_ptr)
    hipMemsetAsync(cnt_src, 0, (char*)row_ptr - (char*)cnt_src, stream);

    count_kernel<<<(E + 255) / 256, 256, 0, stream>>>(src, dst, cnt_src, cnt_dst, rank, E);
    blksum_kernel<<<nb, 256, 0, stream>>>(cnt_src, blksum, n);
    blkscan_kernel<<<1, 256, 0, stream>>>(blksum, blkoff, nb);
    rowptr_kernel<<<nb, 256, 0, stream>>>(cnt_src, blkoff, row_ptr, n);
    dinv_kernel<<<(n + 255) / 256, 256, 0, stream>>>(cnt_dst, dinv, n);
    fill_kernel<<<(E + 255) / 256, 256, 0, stream>>>(src, dst, row_ptr, rank, colb, E);
    hs_kernel<<<(n * 64 + 255) / 256, 256, 0, stream>>>(H, dinv, Hs, n * 64);
    wt_kernel<<<F_DIM, F_DIM, 0, stream>>>(W, Wt);
    gather_kernel<<<(n + 3) / 4, 256, 0, stream>>>(Hs, H0, row_ptr, colb, dinv,
                                                   alpha, irb, n);
    int mtiles = (n + 127) / 128;
    dim3 ggrid(mtiles, 2);
    gemm_kernel<<<ggrid, 256, 0, stream>>>(irb, Wt, out, lamda, lp, n);
}

// Round 6
// 204.247 us; speedup vs baseline: 1.8468x; 1.0979x over previous
//
#include <hip/hip_runtime.h>
#include <math.h>

// GCNII graph convolution, N=50000, F=256, E=800000, f32 in/out.
// R6: atomic-free CSR build via per-block LDS histograms (global atomics were
//     memory-side, 21G/s-bound, 76us). Edges -> 80 chunks x 10000; block =
//     (chunk, node-half) builds u16-packed LDS histogram + per-edge local
//     rank; column sums -> cnt/dinv; scan -> row_ptr; per-chunk bases ->
//     atomic-free fill. GEMM: single-pass 64x256 block tile.

#define F_DIM 256
#define CHUNK 10000

typedef __attribute__((ext_vector_type(4))) float f32x4;
typedef __attribute__((ext_vector_type(8))) short short8;
typedef __attribute__((ext_vector_type(4))) unsigned short u16x4;

static __device__ __forceinline__ unsigned short f2bf(float f) {
    unsigned int u = __float_as_uint(f);
    u += 0x7fffu + ((u >> 16) & 1u);
    return (unsigned short)(u >> 16);
}
static __device__ __forceinline__ float bf2f(unsigned short u) {
    return __uint_as_float((unsigned int)u << 16);
}

// ---- histogram: block = (chunk c, node-half h). LDS = u16-packed counts ----
// word w (global, 0..wpc) covers nodes 2w, 2w+1; half h owns words
// [h*whalf, h*whalf + hcount). Counts <= CHUNK=10000 < 65536, no overflow.

__global__ __launch_bounds__(1024) void hist_kernel(
        const int* __restrict__ src, const int* __restrict__ dst,
        unsigned* __restrict__ histS, unsigned* __restrict__ histD,
        unsigned short* __restrict__ lrank, int E, int wpc, int whalf) {
    __shared__ unsigned hist[12544];
    int c = blockIdx.x >> 1, h = blockIdx.x & 1;
    int tid = threadIdx.x;
    int w0 = h * whalf;
    int hcount = h ? (wpc - whalf) : whalf;
    int e0 = c * CHUNK;
    int e1 = e0 + CHUNK < E ? e0 + CHUNK : E;

    // --- src phase (with local rank) ---
    for (int w = tid; w < hcount; w += 1024) hist[w] = 0;
    __syncthreads();
    for (int e = e0 + tid; e < e1; e += 1024) {
        int s = src[e];
        int wl = (s >> 1) - w0;
        if ((unsigned)wl < (unsigned)hcount) {
            int sh = (s & 1) * 16;
            unsigned old = atomicAdd(&hist[wl], 1u << sh);
            lrank[e] = (unsigned short)((old >> sh) & 0xffffu);
        }
    }
    __syncthreads();
    for (int w = tid; w < hcount; w += 1024)
        histS[(size_t)c * wpc + w0 + w] = hist[w];
    __syncthreads();

    // --- dst phase (counts only) ---
    for (int w = tid; w < hcount; w += 1024) hist[w] = 0;
    __syncthreads();
    for (int e = e0 + tid; e < e1; e += 1024) {
        int d = dst[e];
        int wl = (d >> 1) - w0;
        if ((unsigned)wl < (unsigned)hcount) {
            int sh = (d & 1) * 16;
            atomicAdd(&hist[wl], 1u << sh);
        }
    }
    __syncthreads();
    for (int w = tid; w < hcount; w += 1024)
        histD[(size_t)c * wpc + w0 + w] = hist[w];
}

// ---- column sums over chunks -> cnt_src and dinv -------------------------

__global__ __launch_bounds__(256) void sum_kernel(
        const unsigned* __restrict__ histS, const unsigned* __restrict__ histD,
        int* __restrict__ cnt, float* __restrict__ dinv,
        int wpc, int nchunk, int n) {
    int w = blockIdx.x * 256 + threadIdx.x;
    if (w >= wpc) return;
    unsigned slo = 0, shi = 0, dlo = 0, dhi = 0;
    for (int c = 0; c < nchunk; ++c) {
        unsigned vs = histS[(size_t)c * wpc + w];
        unsigned vd = histD[(size_t)c * wpc + w];
        slo += vs & 0xffffu; shi += vs >> 16;
        dlo += vd & 0xffffu; dhi += vd >> 16;
    }
    int i0 = 2 * w, i1 = 2 * w + 1;
    cnt[i0] = (int)slo;
    dinv[i0] = rsqrtf((float)dlo + 1.0f);
    if (i1 < n) {
        cnt[i1] = (int)shi;
        dinv[i1] = rsqrtf((float)dhi + 1.0f);
    }
}

// ---- hierarchical scan over cnt -> row_ptr --------------------------------

__global__ __launch_bounds__(256) void blksum_kernel(const int* __restrict__ cnt,
                                                     int* __restrict__ blksum, int n) {
    int i = blockIdx.x * 256 + threadIdx.x;
    int v = (i < n) ? cnt[i] : 0;
    int lane = threadIdx.x & 63, w = threadIdx.x >> 6;
    for (int off = 32; off > 0; off >>= 1) v += __shfl_down(v, off, 64);
    __shared__ int ws[4];
    if (lane == 0) ws[w] = v;
    __syncthreads();
    if (threadIdx.x == 0)
        blksum[blockIdx.x] = ws[0] + ws[1] + ws[2] + ws[3];
}

__global__ __launch_bounds__(256) void blkscan_kernel(const int* __restrict__ blksum,
                                                      int* __restrict__ blkoff, int nb) {
    int tid = threadIdx.x;
    int v = (tid < nb) ? blksum[tid] : 0;
    int s = v;
    int lane = tid & 63, w = tid >> 6;
    for (int off = 1; off < 64; off <<= 1) {
        int t = __shfl_up(v, off, 64);
        if (lane >= off) v += t;
    }
    __shared__ int ws[4];
    if (lane == 63) ws[w] = v;
    __syncthreads();
    if (tid == 0) {
        int run = 0;
        for (int i = 0; i < 4; ++i) { int t = ws[i]; ws[i] = run; run += t; }
    }
    __syncthreads();
    if (tid < nb) blkoff[tid] = ws[w] + v - s;   // exclusive
}

__global__ __launch_bounds__(256) void rowptr_kernel(const int* __restrict__ cnt,
                                                     const int* __restrict__ blkoff,
                                                     int* __restrict__ row_ptr, int n) {
    int i = blockIdx.x * 256 + threadIdx.x;
    int tid = threadIdx.x;
    int s = (i < n) ? cnt[i] : 0;
    int v = s;
    int lane = tid & 63, w = tid >> 6;
    for (int off = 1; off < 64; off <<= 1) {
        int t = __shfl_up(v, off, 64);
        if (lane >= off) v += t;
    }
    __shared__ int ws[4];
    if (lane == 63) ws[w] = v;
    __syncthreads();
    if (tid == 0) {
        int run = 0;
        for (int k = 0; k < 4; ++k) { int t = ws[k]; ws[k] = run; run += t; }
    }
    __syncthreads();
    if (i <= n) row_ptr[i] = blkoff[blockIdx.x] + ws[w] + v - s;
}

// ---- per-chunk base offsets: baseG[c][node] -------------------------------

__global__ __launch_bounds__(256) void base_kernel(
        const unsigned* __restrict__ histS, const int* __restrict__ row_ptr,
        unsigned* __restrict__ baseG, int wpc, int nchunk, int n) {
    int w = blockIdx.x * 256 + threadIdx.x;
    if (w >= wpc) return;
    unsigned run_lo = (unsigned)row_ptr[2 * w];
    unsigned run_hi = (2 * w + 1 <= n) ? (unsigned)row_ptr[2 * w + 1] : 0u;
    size_t stride = (size_t)2 * wpc;
    for (int c = 0; c < nchunk; ++c) {
        unsigned vs = histS[(size_t)c * wpc + w];
        baseG[c * stride + 2 * w]     = run_lo;
        baseG[c * stride + 2 * w + 1] = run_hi;
        run_lo += vs & 0xffffu;
        run_hi += vs >> 16;
    }
}

// ---- atomic-free fill -----------------------------------------------------

__global__ __launch_bounds__(256) void fill_kernel(
        const int* __restrict__ src, const int* __restrict__ dst,
        const unsigned* __restrict__ baseG, const unsigned short* __restrict__ lrank,
        int* __restrict__ col, int E, int wpc) {
    int e = blockIdx.x * 256 + threadIdx.x;
    if (e < E) {
        int c = e / CHUNK;
        int s = src[e];
        unsigned pos = baseG[(size_t)c * (2 * wpc) + s] + lrank[e];
        col[pos] = dst[e];
    }
}

// ---- Hs = bf16(H * dinv[row]) ---------------------------------------------

__global__ __launch_bounds__(256) void hs_kernel(const float* __restrict__ H,
                                                 const float* __restrict__ dinv,
                                                 unsigned short* __restrict__ Hs,
                                                 int total4) {
    int i = blockIdx.x * 256 + threadIdx.x;   // index in f32x4 / u16x4 units
    if (i >= total4) return;
    int row = i >> 6;                          // 64 x f32x4 per row
    float d = dinv[row];
    f32x4 x = ((const f32x4*)H)[i];
    u16x4 o;
    o[0] = f2bf(x[0] * d); o[1] = f2bf(x[1] * d);
    o[2] = f2bf(x[2] * d); o[3] = f2bf(x[3] * d);
    ((u16x4*)Hs)[i] = o;
}

// ---- W transpose to bf16 (Wt[n][k]) ---------------------------------------

__global__ void wt_kernel(const float* __restrict__ W, unsigned short* __restrict__ Wt) {
    int n = blockIdx.x;
    int k = threadIdx.x;
    Wt[n * F_DIM + k] = f2bf(W[k * F_DIM + n]);
}

// ---- gather: one wave per row, 512B coalesced loads, 8-deep edge unroll ----

#define ACC(A, h) { A[0] += bf2f(h[0]); A[1] += bf2f(h[1]); \
                    A[2] += bf2f(h[2]); A[3] += bf2f(h[3]); }

__global__ __launch_bounds__(256) void gather_kernel(
        const unsigned short* __restrict__ Hs, const float* __restrict__ H0,
        const int* __restrict__ row_ptr, const int* __restrict__ col,
        const float* __restrict__ dinv, const float* __restrict__ alpha_p,
        unsigned short* __restrict__ irb, int n) {
    int wave = threadIdx.x >> 6;
    int lane = threadIdx.x & 63;
    int row = blockIdx.x * 4 + wave;
    if (row >= n) return;
    float alpha = alpha_p[0];
    const u16x4* Hs4 = (const u16x4*)Hs;

    int beg = row_ptr[row], end = row_ptr[row + 1];
    f32x4 a0 = 0.0f, a1 = 0.0f, a2 = 0.0f, a3 = 0.0f;
    int e = beg;
    for (; e + 8 <= end; e += 8) {             // 8 gathers in flight
        int j0 = col[e+0], j1 = col[e+1], j2 = col[e+2], j3 = col[e+3];
        int j4 = col[e+4], j5 = col[e+5], j6 = col[e+6], j7 = col[e+7];
        u16x4 h0 = Hs4[j0*64+lane], h1 = Hs4[j1*64+lane];
        u16x4 h2 = Hs4[j2*64+lane], h3 = Hs4[j3*64+lane];
        u16x4 h4 = Hs4[j4*64+lane], h5 = Hs4[j5*64+lane];
        u16x4 h6 = Hs4[j6*64+lane], h7 = Hs4[j7*64+lane];
        ACC(a0, h0) ACC(a1, h1) ACC(a2, h2) ACC(a3, h3)
        ACC(a0, h4) ACC(a1, h5) ACC(a2, h6) ACC(a3, h7)
    }
    for (; e + 4 <= end; e += 4) {
        int j0 = col[e+0], j1 = col[e+1], j2 = col[e+2], j3 = col[e+3];
        u16x4 h0 = Hs4[j0*64+lane], h1 = Hs4[j1*64+lane];
        u16x4 h2 = Hs4[j2*64+lane], h3 = Hs4[j3*64+lane];
        ACC(a0, h0) ACC(a1, h1) ACC(a2, h2) ACC(a3, h3)
    }
    for (; e < end; ++e) {
        int j = col[e];
        u16x4 h = Hs4[j*64+lane];
        ACC(a0, h)
    }
    // self loop: H/deg = Hs * dinv  =>  PH = dinv[row] * (sum + Hs_row)
    u16x4 hr = Hs4[row*64+lane];
    ACC(a2, hr)
    f32x4 acc = (a0 + a1) + (a2 + a3);
    float di = dinv[row];
    f32x4 h0v = ((const f32x4*)H0)[row * 64 + lane];
    f32x4 init = (1.0f - alpha) * (di * acc) + alpha * h0v;
    u16x4 o;
    o[0] = f2bf(init[0]); o[1] = f2bf(init[1]);
    o[2] = f2bf(init[2]); o[3] = f2bf(init[3]);
    ((u16x4*)irb)[row * 64 + lane] = o;
}

// ---- GEMM: out = (1-beta)*irb + beta*(irb @ W), bf16 MFMA 16x16x32 --------
// 4 waves/block; block tile 64 rows x 256 cols (full N, A read once);
// wave w owns cols [w*64, w*64+64); K = 256 in 8 steps.

__global__ __launch_bounds__(256) void gemm_kernel(
        const unsigned short* __restrict__ irb, const unsigned short* __restrict__ Wt,
        float* __restrict__ out, const float* __restrict__ lamda_p,
        const int* __restrict__ l_p, int M) {
    int w = threadIdx.x >> 6;
    int mr = blockIdx.x * 64;
    int nc = w * 64;
    int lane = threadIdx.x & 63;
    int lo = lane & 15, hi = lane >> 4;
    float beta = logf(lamda_p[0] / (float)l_p[0] + 1.0f);
    float ob = 1.0f - beta;

    f32x4 acc[4][4] = {};
    for (int kk = 0; kk < 8; ++kk) {
        int kb = kk * 32 + hi * 8;
        short8 a[4], b[4];
        for (int am = 0; am < 4; ++am) {
            int row = mr + am * 16 + lo;
            a[am] = (row < M) ? *(const short8*)(irb + (size_t)row * F_DIM + kb)
                              : (short8)0;
        }
        for (int bn = 0; bn < 4; ++bn) {
            int cb = nc + bn * 16 + lo;
            b[bn] = *(const short8*)(Wt + cb * F_DIM + kb);
        }
        for (int am = 0; am < 4; ++am)
            for (int bn = 0; bn < 4; ++bn)
                acc[am][bn] = __builtin_amdgcn_mfma_f32_16x16x32_bf16(
                    a[am], b[bn], acc[am][bn], 0, 0, 0);
    }

    // C/D layout: col = lane&15, row = (lane>>4)*4 + reg   [m89-verified]
    for (int am = 0; am < 4; ++am) {
        int rbase = mr + am * 16 + hi * 4;
        for (int r = 0; r < 4; ++r) {
            int row = rbase + r;
            if (row >= M) continue;
            for (int bn = 0; bn < 4; ++bn) {
                int c2 = nc + bn * 16 + lo;
                size_t idx = (size_t)row * F_DIM + c2;
                out[idx] = ob * bf2f(irb[idx]) + beta * acc[am][bn][r];
            }
        }
    }
}

// ---- launch ---------------------------------------------------------------

extern "C" void kernel_launch(void* const* d_in, const int* in_sizes, int n_in,
                              void* d_out, int out_size, void* d_ws, size_t ws_size,
                              hipStream_t stream) {
    const float* H     = (const float*)d_in[0];
    const int*   ei    = (const int*)d_in[1];
    const float* H0    = (const float*)d_in[2];
    const float* W     = (const float*)d_in[3];
    const float* lamda = (const float*)d_in[4];
    const float* alpha = (const float*)d_in[5];
    const int*   lp    = (const int*)d_in[6];

    int n = in_sizes[0] / F_DIM;
    int E = in_sizes[1] / 2;
    const int* src = ei;
    const int* dst = ei + E;
    float* out = (float*)d_out;

    int wpc = (n + 1) / 2;                 // packed words per chunk (25000)
    int whalf = (wpc + 1) / 2;             // words in half 0 (12500)
    int nchunk = (E + CHUNK - 1) / CHUNK;  // 80
    int nb = (n + 256) / 256;              // scan blocks covering 0..n (196)

    char* ws = (char*)d_ws;
    size_t off = 0;
    auto alloc = [&](size_t bytes) -> void* {
        void* p = ws + off;
        off += (bytes + 255) & ~(size_t)255;
        return p;
    };
    unsigned* histS = (unsigned*)alloc((size_t)nchunk * wpc * 4);   // 8 MB
    unsigned* histD = (unsigned*)alloc((size_t)nchunk * wpc * 4);   // 8 MB (dead after sum)
    unsigned* baseG = (unsigned*)alloc((size_t)nchunk * 2 * wpc * 4); // 16 MB
    unsigned short* lrank = (unsigned short*)alloc((size_t)E * 2);
    int* cnt     = (int*)alloc((size_t)n * 4);
    int* row_ptr = (int*)alloc(((size_t)n + 1) * 4);
    int* blksum  = (int*)alloc((size_t)nb * 4);
    int* blkoff  = (int*)alloc((size_t)nb * 4);
    float* dinv  = (float*)alloc((size_t)n * 4);
    int* colb    = (int*)alloc((size_t)E * 4);
    unsigned short* Wt  = (unsigned short*)alloc((size_t)F_DIM * F_DIM * 2);
    unsigned short* Hs  = (unsigned short*)alloc((size_t)n * F_DIM * 2);
    unsigned short* irb = (unsigned short*)alloc(((size_t)n + 64) * F_DIM * 2);

    hist_kernel<<<nchunk * 2, 1024, 0, stream>>>(src, dst, histS, histD, lrank,
                                                 E, wpc, whalf);
    int wgrid = (wpc + 255) / 256;
    sum_kernel<<<wgrid, 256, 0, stream>>>(histS, histD, cnt, dinv, wpc, nchunk, n);
    blksum_kernel<<<nb, 256, 0, stream>>>(cnt, blksum, n);
    blkscan_kernel<<<1, 256, 0, stream>>>(blksum, blkoff, nb);
    rowptr_kernel<<<nb, 256, 0, stream>>>(cnt, blkoff, row_ptr, n);
    base_kernel<<<wgrid, 256, 0, stream>>>(histS, row_ptr, baseG, wpc, nchunk, n);
    fill_kernel<<<(E + 255) / 256, 256, 0, stream>>>(src, dst, baseG, lrank,
                                                     colb, E, wpc);
    hs_kernel<<<(n * 64 + 255) / 256, 256, 0, stream>>>(H, dinv, Hs, n * 64);
    wt_kernel<<<F_DIM, F_DIM, 0, stream>>>(W, Wt);
    gather_kernel<<<(n + 3) / 4, 256, 0, stream>>>(Hs, H0, row_ptr, colb, dinv,
                                                   alpha, irb, n);
    int mtiles = (n + 63) / 64;
    gemm_kernel<<<mtiles, 256, 0, stream>>>(irb, Wt, out, lamda, lp, n);
}

// Round 7
// 202.801 us; speedup vs baseline: 1.8600x; 1.0071x over previous
//
#include <hip/hip_runtime.h>
#include <math.h>

// GCNII graph convolution, N=50000, F=256, E=800000, f32 in/out.
// R7: GEMM fused into gather (16-row LDS tile per block, 4 waves x 64-col
//     strips, one barrier) -- irb buffer and gemm kernel eliminated.
//     hist split into 4 independent single-phase block types.
//     base fused into sum (fill adds row_ptr itself, L2-resident).

#define F_DIM 256
#define CHUNK 10000

typedef __attribute__((ext_vector_type(4))) float f32x4;
typedef __attribute__((ext_vector_type(8))) short short8;
typedef __attribute__((ext_vector_type(4))) unsigned short u16x4;

static __device__ __forceinline__ unsigned short f2bf(float f) {
    unsigned int u = __float_as_uint(f);
    u += 0x7fffu + ((u >> 16) & 1u);
    return (unsigned short)(u >> 16);
}
static __device__ __forceinline__ float bf2f(unsigned short u) {
    return __uint_as_float((unsigned int)u << 16);
}

// ---- histogram: block = (chunk c, half h, which). u16-packed LDS counts ----
// word w covers nodes 2w,2w+1; half h owns words [h*whalf, h*whalf+hcount).

__global__ __launch_bounds__(1024) void hist_kernel(
        const int* __restrict__ src, const int* __restrict__ dst,
        unsigned* __restrict__ histS, unsigned* __restrict__ histD,
        unsigned short* __restrict__ lrank, int E, int wpc, int whalf) {
    __shared__ unsigned hist[12544];
    int b = blockIdx.x;
    int which = b & 1, h = (b >> 1) & 1, c = b >> 2;
    int tid = threadIdx.x;
    int w0 = h * whalf;
    int hcount = h ? (wpc - whalf) : whalf;
    int e0 = c * CHUNK;
    int e1 = e0 + CHUNK < E ? e0 + CHUNK : E;
    const int* eptr = which ? dst : src;
    unsigned* outh = which ? histD : histS;

    for (int w = tid; w < hcount; w += 1024) hist[w] = 0;
    __syncthreads();
    for (int e = e0 + tid; e < e1; e += 1024) {
        int s = eptr[e];
        int wl = (s >> 1) - w0;
        if ((unsigned)wl < (unsigned)hcount) {
            int sh = (s & 1) * 16;
            unsigned old = atomicAdd(&hist[wl], 1u << sh);
            if (!which) lrank[e] = (unsigned short)((old >> sh) & 0xffffu);
        }
    }
    __syncthreads();
    for (int w = tid; w < hcount; w += 1024)
        outh[(size_t)c * wpc + w0 + w] = hist[w];
}

// ---- one histS/histD pass: cnt, dinv, and per-chunk local bases -----------

__global__ __launch_bounds__(256) void sumbase_kernel(
        const unsigned* __restrict__ histS, const unsigned* __restrict__ histD,
        int* __restrict__ cnt, float* __restrict__ dinv,
        unsigned* __restrict__ baseL, int wpc, int nchunk, int n) {
    int w = blockIdx.x * 256 + threadIdx.x;
    if (w >= wpc) return;
    size_t stride2 = (size_t)2 * wpc;
    unsigned slo = 0, shi = 0, dlo = 0, dhi = 0;
    for (int c = 0; c < nchunk; ++c) {
        unsigned vs = histS[(size_t)c * wpc + w];
        unsigned vd = histD[(size_t)c * wpc + w];
        baseL[c * stride2 + 2 * w]     = slo;
        baseL[c * stride2 + 2 * w + 1] = shi;
        slo += vs & 0xffffu; shi += vs >> 16;
        dlo += vd & 0xffffu; dhi += vd >> 16;
    }
    int i0 = 2 * w, i1 = 2 * w + 1;
    cnt[i0] = (int)slo;
    dinv[i0] = rsqrtf((float)dlo + 1.0f);
    if (i1 < n) {
        cnt[i1] = (int)shi;
        dinv[i1] = rsqrtf((float)dhi + 1.0f);
    }
}

// ---- hierarchical scan over cnt -> row_ptr --------------------------------

__global__ __launch_bounds__(256) void blksum_kernel(const int* __restrict__ cnt,
                                                     int* __restrict__ blksum, int n) {
    int i = blockIdx.x * 256 + threadIdx.x;
    int v = (i < n) ? cnt[i] : 0;
    int lane = threadIdx.x & 63, w = threadIdx.x >> 6;
    for (int off = 32; off > 0; off >>= 1) v += __shfl_down(v, off, 64);
    __shared__ int ws[4];
    if (lane == 0) ws[w] = v;
    __syncthreads();
    if (threadIdx.x == 0)
        blksum[blockIdx.x] = ws[0] + ws[1] + ws[2] + ws[3];
}

__global__ __launch_bounds__(256) void blkscan_kernel(const int* __restrict__ blksum,
                                                      int* __restrict__ blkoff, int nb) {
    int tid = threadIdx.x;
    int v = (tid < nb) ? blksum[tid] : 0;
    int s = v;
    int lane = tid & 63, w = tid >> 6;
    for (int off = 1; off < 64; off <<= 1) {
        int t = __shfl_up(v, off, 64);
        if (lane >= off) v += t;
    }
    __shared__ int ws[4];
    if (lane == 63) ws[w] = v;
    __syncthreads();
    if (tid == 0) {
        int run = 0;
        for (int i = 0; i < 4; ++i) { int t = ws[i]; ws[i] = run; run += t; }
    }
    __syncthreads();
    if (tid < nb) blkoff[tid] = ws[w] + v - s;   // exclusive
}

__global__ __launch_bounds__(256) void rowptr_kernel(const int* __restrict__ cnt,
                                                     const int* __restrict__ blkoff,
                                                     int* __restrict__ row_ptr, int n) {
    int i = blockIdx.x * 256 + threadIdx.x;
    int tid = threadIdx.x;
    int s = (i < n) ? cnt[i] : 0;
    int v = s;
    int lane = tid & 63, w = tid >> 6;
    for (int off = 1; off < 64; off <<= 1) {
        int t = __shfl_up(v, off, 64);
        if (lane >= off) v += t;
    }
    __shared__ int ws[4];
    if (lane == 63) ws[w] = v;
    __syncthreads();
    if (tid == 0) {
        int run = 0;
        for (int k = 0; k < 4; ++k) { int t = ws[k]; ws[k] = run; run += t; }
    }
    __syncthreads();
    if (i <= n) row_ptr[i] = blkoff[blockIdx.x] + ws[w] + v - s;
}

// ---- atomic-free fill: pos = row_ptr[s] + baseL[c][s] + lrank[e] ----------

__global__ __launch_bounds__(256) void fill_kernel(
        const int* __restrict__ src, const int* __restrict__ dst,
        const int* __restrict__ row_ptr, const unsigned* __restrict__ baseL,
        const unsigned short* __restrict__ lrank,
        int* __restrict__ col, int E, int wpc) {
    int e = blockIdx.x * 256 + threadIdx.x;
    if (e < E) {
        int c = e / CHUNK;
        int s = src[e];
        unsigned pos = (unsigned)row_ptr[s] + baseL[(size_t)c * (2 * wpc) + s]
                     + lrank[e];
        col[pos] = dst[e];
    }
}

// ---- Hs = bf16(H * dinv[row]) ---------------------------------------------

__global__ __launch_bounds__(256) void hs_kernel(const float* __restrict__ H,
                                                 const float* __restrict__ dinv,
                                                 unsigned short* __restrict__ Hs,
                                                 int total4) {
    int i = blockIdx.x * 256 + threadIdx.x;   // index in f32x4 / u16x4 units
    if (i >= total4) return;
    int row = i >> 6;                          // 64 x f32x4 per row
    float d = dinv[row];
    f32x4 x = ((const f32x4*)H)[i];
    u16x4 o;
    o[0] = f2bf(x[0] * d); o[1] = f2bf(x[1] * d);
    o[2] = f2bf(x[2] * d); o[3] = f2bf(x[3] * d);
    ((u16x4*)Hs)[i] = o;
}

// ---- W transpose to bf16 (Wt[n][k]) ---------------------------------------

__global__ void wt_kernel(const float* __restrict__ W, unsigned short* __restrict__ Wt) {
    int n = blockIdx.x;
    int k = threadIdx.x;
    Wt[n * F_DIM + k] = f2bf(W[k * F_DIM + n]);
}

// ---- fused gather + GEMM ---------------------------------------------------
// Block = 4 waves; 16 rows. Phase 1: wave w gathers rows base+w*4..+3 (512B
// coalesced loads, 8-deep unroll) -> init rows in LDS (bf16, stride 264 to
// break bank conflicts). Phase 2: wave w computes out[rows][w*64..w*64+64) =
// (1-beta)*init + beta*(init @ W) via 32x mfma 16x16x32.

#define ACC(A, h) { A[0] += bf2f(h[0]); A[1] += bf2f(h[1]); \
                    A[2] += bf2f(h[2]); A[3] += bf2f(h[3]); }

__global__ __launch_bounds__(256) void fused_kernel(
        const unsigned short* __restrict__ Hs, const float* __restrict__ H0,
        const int* __restrict__ row_ptr, const int* __restrict__ col,
        const float* __restrict__ dinv, const float* __restrict__ alpha_p,
        const unsigned short* __restrict__ Wt, float* __restrict__ out,
        const float* __restrict__ lamda_p, const int* __restrict__ l_p, int n) {
    __shared__ __align__(16) unsigned short initL[16][264];
    int wave = threadIdx.x >> 6;
    int lane = threadIdx.x & 63;
    int rbase = blockIdx.x * 16;
    float alpha = alpha_p[0];
    const u16x4* Hs4 = (const u16x4*)Hs;

    // ---- phase 1: gather 4 rows per wave ----
    for (int q = 0; q < 4; ++q) {
        int r = wave * 4 + q;
        int row = rbase + r;
        if (row >= n) break;
        int beg = row_ptr[row], end = row_ptr[row + 1];
        f32x4 a0 = 0.0f, a1 = 0.0f, a2 = 0.0f, a3 = 0.0f;
        int e = beg;
        for (; e + 8 <= end; e += 8) {             // 8 gathers in flight
            int j0 = col[e+0], j1 = col[e+1], j2 = col[e+2], j3 = col[e+3];
            int j4 = col[e+4], j5 = col[e+5], j6 = col[e+6], j7 = col[e+7];
            u16x4 h0 = Hs4[j0*64+lane], h1 = Hs4[j1*64+lane];
            u16x4 h2 = Hs4[j2*64+lane], h3 = Hs4[j3*64+lane];
            u16x4 h4 = Hs4[j4*64+lane], h5 = Hs4[j5*64+lane];
            u16x4 h6 = Hs4[j6*64+lane], h7 = Hs4[j7*64+lane];
            ACC(a0, h0) ACC(a1, h1) ACC(a2, h2) ACC(a3, h3)
            ACC(a0, h4) ACC(a1, h5) ACC(a2, h6) ACC(a3, h7)
        }
        for (; e + 4 <= end; e += 4) {
            int j0 = col[e+0], j1 = col[e+1], j2 = col[e+2], j3 = col[e+3];
            u16x4 h0 = Hs4[j0*64+lane], h1 = Hs4[j1*64+lane];
            u16x4 h2 = Hs4[j2*64+lane], h3 = Hs4[j3*64+lane];
            ACC(a0, h0) ACC(a1, h1) ACC(a2, h2) ACC(a3, h3)
        }
        for (; e < end; ++e) {
            int j = col[e];
            u16x4 h = Hs4[j*64+lane];
            ACC(a0, h)
        }
        // self loop: H/deg = Hs * dinv  =>  PH = dinv[row] * (sum + Hs_row)
        u16x4 hr = Hs4[row*64+lane];
        ACC(a2, hr)
        f32x4 acc = (a0 + a1) + (a2 + a3);
        float di = dinv[row];
        f32x4 h0v = ((const f32x4*)H0)[row * 64 + lane];
        f32x4 init = (1.0f - alpha) * (di * acc) + alpha * h0v;
        u16x4 o;
        o[0] = f2bf(init[0]); o[1] = f2bf(init[1]);
        o[2] = f2bf(init[2]); o[3] = f2bf(init[3]);
        *(u16x4*)&initL[r][lane * 4] = o;
    }
    __syncthreads();

    // ---- phase 2: 16x64 GEMM strip per wave ----
    int lo = lane & 15, hi = lane >> 4;
    int nc = wave * 64;
    float beta = logf(lamda_p[0] / (float)l_p[0] + 1.0f);
    float ob = 1.0f - beta;

    f32x4 acc[4] = {};
    for (int kk = 0; kk < 8; ++kk) {
        int kb = kk * 32 + hi * 8;
        short8 a = *(const short8*)&initL[lo][kb];       // A row = lo
        for (int bn = 0; bn < 4; ++bn) {
            short8 b = *(const short8*)(Wt + (size_t)(nc + bn * 16 + lo) * F_DIM + kb);
            acc[bn] = __builtin_amdgcn_mfma_f32_16x16x32_bf16(a, b, acc[bn], 0, 0, 0);
        }
    }
    // C/D layout: col = lane&15, row = (lane>>4)*4 + reg   [m89-verified]
    for (int bn = 0; bn < 4; ++bn) {
        for (int r = 0; r < 4; ++r) {
            int rt = hi * 4 + r;
            int row = rbase + rt;
            if (row >= n) continue;
            int c2 = nc + bn * 16 + lo;
            float iv = bf2f(initL[rt][c2]);
            out[(size_t)row * F_DIM + c2] = ob * iv + beta * acc[bn][r];
        }
    }
}

// ---- launch ---------------------------------------------------------------

extern "C" void kernel_launch(void* const* d_in, const int* in_sizes, int n_in,
                              void* d_out, int out_size, void* d_ws, size_t ws_size,
                              hipStream_t stream) {
    const float* H     = (const float*)d_in[0];
    const int*   ei    = (const int*)d_in[1];
    const float* H0    = (const float*)d_in[2];
    const float* W     = (const float*)d_in[3];
    const float* lamda = (const float*)d_in[4];
    const float* alpha = (const float*)d_in[5];
    const int*   lp    = (const int*)d_in[6];

    int n = in_sizes[0] / F_DIM;
    int E = in_sizes[1] / 2;
    const int* src = ei;
    const int* dst = ei + E;
    float* out = (float*)d_out;

    int wpc = (n + 1) / 2;                 // packed words per chunk (25000)
    int whalf = (wpc + 1) / 2;             // words in half 0 (12500)
    int nchunk = (E + CHUNK - 1) / CHUNK;  // 80
    int nb = (n + 256) / 256;              // scan blocks covering 0..n (196)

    char* ws = (char*)d_ws;
    size_t off = 0;
    auto alloc = [&](size_t bytes) -> void* {
        void* p = ws + off;
        off += (bytes + 255) & ~(size_t)255;
        return p;
    };
    unsigned* histS = (unsigned*)alloc((size_t)nchunk * wpc * 4);     // 8 MB
    unsigned* histD = (unsigned*)alloc((size_t)nchunk * wpc * 4);     // 8 MB
    unsigned* baseL = (unsigned*)alloc((size_t)nchunk * 2 * wpc * 4); // 16 MB
    unsigned short* lrank = (unsigned short*)alloc((size_t)E * 2);
    int* cnt     = (int*)alloc((size_t)n * 4);
    int* row_ptr = (int*)alloc(((size_t)n + 1) * 4);
    int* blksum  = (int*)alloc((size_t)nb * 4);
    int* blkoff  = (int*)alloc((size_t)nb * 4);
    float* dinv  = (float*)alloc((size_t)n * 4);
    int* colb    = (int*)alloc((size_t)E * 4);
    unsigned short* Wt  = (unsigned short*)alloc((size_t)F_DIM * F_DIM * 2);
    unsigned short* Hs  = (unsigned short*)alloc((size_t)n * F_DIM * 2);

    hist_kernel<<<nchunk * 4, 1024, 0, stream>>>(src, dst, histS, histD, lrank,
                                                 E, wpc, whalf);
    int wgrid = (wpc + 255) / 256;
    sumbase_kernel<<<wgrid, 256, 0, stream>>>(histS, histD, cnt, dinv, baseL,
                                              wpc, nchunk, n);
    blksum_kernel<<<nb, 256, 0, stream>>>(cnt, blksum, n);
    blkscan_kernel<<<1, 256, 0, stream>>>(blksum, blkoff, nb);
    rowptr_kernel<<<nb, 256, 0, stream>>>(cnt, blkoff, row_ptr, n);
    fill_kernel<<<(E + 255) / 256, 256, 0, stream>>>(src, dst, row_ptr, baseL,
                                                     lrank, colb, E, wpc);
    hs_kernel<<<(n * 64 + 255) / 256, 256, 0, stream>>>(H, dinv, Hs, n * 64);
    wt_kernel<<<F_DIM, F_DIM, 0, stream>>>(W, Wt);
    fused_kernel<<<(n + 15) / 16, 256, 0, stream>>>(Hs, H0, row_ptr, colb, dinv,
                                                    alpha, Wt, out, lamda, lp, n);
}

// Round 8
// 190.065 us; speedup vs baseline: 1.9846x; 1.0670x over previous
//
#include <hip/hip_runtime.h>
#include <math.h>

// GCNII graph convolution, N=50000, F=256, E=800000, f32 in/out.
// R8: UNFUSE gather/gemm (R7 fusion's barrier made block time = max of 16 row
//     degrees; occupancy 73->38%). Keep R7 CSR pipeline (4-way hist, sumbase,
//     atomic-free fill). Gather: 16-deep unroll (8-deep gave 109->70us).
//     wt merged into hs (one launch).

#define F_DIM 256
#define CHUNK 10000

typedef __attribute__((ext_vector_type(4))) float f32x4;
typedef __attribute__((ext_vector_type(8))) short short8;
typedef __attribute__((ext_vector_type(4))) unsigned short u16x4;

static __device__ __forceinline__ unsigned short f2bf(float f) {
    unsigned int u = __float_as_uint(f);
    u += 0x7fffu + ((u >> 16) & 1u);
    return (unsigned short)(u >> 16);
}
static __device__ __forceinline__ float bf2f(unsigned short u) {
    return __uint_as_float((unsigned int)u << 16);
}

// ---- histogram: block = (chunk c, half h, which). u16-packed LDS counts ----

__global__ __launch_bounds__(1024) void hist_kernel(
        const int* __restrict__ src, const int* __restrict__ dst,
        unsigned* __restrict__ histS, unsigned* __restrict__ histD,
        unsigned short* __restrict__ lrank, int E, int wpc, int whalf) {
    __shared__ unsigned hist[12544];
    int b = blockIdx.x;
    int which = b & 1, h = (b >> 1) & 1, c = b >> 2;
    int tid = threadIdx.x;
    int w0 = h * whalf;
    int hcount = h ? (wpc - whalf) : whalf;
    int e0 = c * CHUNK;
    int e1 = e0 + CHUNK < E ? e0 + CHUNK : E;
    const int* eptr = which ? dst : src;
    unsigned* outh = which ? histD : histS;

    for (int w = tid; w < hcount; w += 1024) hist[w] = 0;
    __syncthreads();
    for (int e = e0 + tid; e < e1; e += 1024) {
        int s = eptr[e];
        int wl = (s >> 1) - w0;
        if ((unsigned)wl < (unsigned)hcount) {
            int sh = (s & 1) * 16;
            unsigned old = atomicAdd(&hist[wl], 1u << sh);
            if (!which) lrank[e] = (unsigned short)((old >> sh) & 0xffffu);
        }
    }
    __syncthreads();
    for (int w = tid; w < hcount; w += 1024)
        outh[(size_t)c * wpc + w0 + w] = hist[w];
}

// ---- one histS/histD pass: cnt, dinv, and per-chunk local bases -----------

__global__ __launch_bounds__(256) void sumbase_kernel(
        const unsigned* __restrict__ histS, const unsigned* __restrict__ histD,
        int* __restrict__ cnt, float* __restrict__ dinv,
        unsigned* __restrict__ baseL, int wpc, int nchunk, int n) {
    int w = blockIdx.x * 256 + threadIdx.x;
    if (w >= wpc) return;
    size_t stride2 = (size_t)2 * wpc;
    unsigned slo = 0, shi = 0, dlo = 0, dhi = 0;
    for (int c = 0; c < nchunk; ++c) {
        unsigned vs = histS[(size_t)c * wpc + w];
        unsigned vd = histD[(size_t)c * wpc + w];
        baseL[c * stride2 + 2 * w]     = slo;
        baseL[c * stride2 + 2 * w + 1] = shi;
        slo += vs & 0xffffu; shi += vs >> 16;
        dlo += vd & 0xffffu; dhi += vd >> 16;
    }
    int i0 = 2 * w, i1 = 2 * w + 1;
    cnt[i0] = (int)slo;
    dinv[i0] = rsqrtf((float)dlo + 1.0f);
    if (i1 < n) {
        cnt[i1] = (int)shi;
        dinv[i1] = rsqrtf((float)dhi + 1.0f);
    }
}

// ---- hierarchical scan over cnt -> row_ptr --------------------------------

__global__ __launch_bounds__(256) void blksum_kernel(const int* __restrict__ cnt,
                                                     int* __restrict__ blksum, int n) {
    int i = blockIdx.x * 256 + threadIdx.x;
    int v = (i < n) ? cnt[i] : 0;
    int lane = threadIdx.x & 63, w = threadIdx.x >> 6;
    for (int off = 32; off > 0; off >>= 1) v += __shfl_down(v, off, 64);
    __shared__ int ws[4];
    if (lane == 0) ws[w] = v;
    __syncthreads();
    if (threadIdx.x == 0)
        blksum[blockIdx.x] = ws[0] + ws[1] + ws[2] + ws[3];
}

__global__ __launch_bounds__(256) void blkscan_kernel(const int* __restrict__ blksum,
                                                      int* __restrict__ blkoff, int nb) {
    int tid = threadIdx.x;
    int v = (tid < nb) ? blksum[tid] : 0;
    int s = v;
    int lane = tid & 63, w = tid >> 6;
    for (int off = 1; off < 64; off <<= 1) {
        int t = __shfl_up(v, off, 64);
        if (lane >= off) v += t;
    }
    __shared__ int ws[4];
    if (lane == 63) ws[w] = v;
    __syncthreads();
    if (tid == 0) {
        int run = 0;
        for (int i = 0; i < 4; ++i) { int t = ws[i]; ws[i] = run; run += t; }
    }
    __syncthreads();
    if (tid < nb) blkoff[tid] = ws[w] + v - s;   // exclusive
}

__global__ __launch_bounds__(256) void rowptr_kernel(const int* __restrict__ cnt,
                                                     const int* __restrict__ blkoff,
                                                     int* __restrict__ row_ptr, int n) {
    int i = blockIdx.x * 256 + threadIdx.x;
    int tid = threadIdx.x;
    int s = (i < n) ? cnt[i] : 0;
    int v = s;
    int lane = tid & 63, w = tid >> 6;
    for (int off = 1; off < 64; off <<= 1) {
        int t = __shfl_up(v, off, 64);
        if (lane >= off) v += t;
    }
    __shared__ int ws[4];
    if (lane == 63) ws[w] = v;
    __syncthreads();
    if (tid == 0) {
        int run = 0;
        for (int k = 0; k < 4; ++k) { int t = ws[k]; ws[k] = run; run += t; }
    }
    __syncthreads();
    if (i <= n) row_ptr[i] = blkoff[blockIdx.x] + ws[w] + v - s;
}

// ---- atomic-free fill: pos = row_ptr[s] + baseL[c][s] + lrank[e] ----------

__global__ __launch_bounds__(256) void fill_kernel(
        const int* __restrict__ src, const int* __restrict__ dst,
        const int* __restrict__ row_ptr, const unsigned* __restrict__ baseL,
        const unsigned short* __restrict__ lrank,
        int* __restrict__ col, int E, int wpc) {
    int e = blockIdx.x * 256 + threadIdx.x;
    if (e < E) {
        int c = e / CHUNK;
        int s = src[e];
        unsigned pos = (unsigned)row_ptr[s] + baseL[(size_t)c * (2 * wpc) + s]
                     + lrank[e];
        col[pos] = dst[e];
    }
}

// ---- Hs = bf16(H * dinv[row])  +  Wt = bf16(W^T)  (merged launch) ----------

__global__ __launch_bounds__(256) void hswt_kernel(const float* __restrict__ H,
                                                   const float* __restrict__ dinv,
                                                   unsigned short* __restrict__ Hs,
                                                   const float* __restrict__ W,
                                                   unsigned short* __restrict__ Wt,
                                                   int total4) {
    int i = blockIdx.x * 256 + threadIdx.x;   // index in f32x4 / u16x4 units
    if (i < total4) {
        int row = i >> 6;                      // 64 x f32x4 per row
        float d = dinv[row];
        f32x4 x = ((const f32x4*)H)[i];
        u16x4 o;
        o[0] = f2bf(x[0] * d); o[1] = f2bf(x[1] * d);
        o[2] = f2bf(x[2] * d); o[3] = f2bf(x[3] * d);
        ((u16x4*)Hs)[i] = o;
    } else {
        int t = i - total4;                    // 0 .. 65535 -> Wt transpose
        if (t < F_DIM * F_DIM) {
            int nn = t >> 8, kk = t & 255;
            Wt[nn * F_DIM + kk] = f2bf(W[kk * F_DIM + nn]);
        }
    }
}

// ---- gather: one wave per row, 512B loads, 16-deep edge unroll -------------

#define ACC(A, h) { A[0] += bf2f(h[0]); A[1] += bf2f(h[1]); \
                    A[2] += bf2f(h[2]); A[3] += bf2f(h[3]); }

__global__ __launch_bounds__(256) void gather_kernel(
        const unsigned short* __restrict__ Hs, const float* __restrict__ H0,
        const int* __restrict__ row_ptr, const int* __restrict__ col,
        const float* __restrict__ dinv, const float* __restrict__ alpha_p,
        unsigned short* __restrict__ irb, int n) {
    int wave = threadIdx.x >> 6;
    int lane = threadIdx.x & 63;
    int row = blockIdx.x * 4 + wave;
    if (row >= n) return;
    float alpha = alpha_p[0];
    const u16x4* Hs4 = (const u16x4*)Hs;

    int beg = row_ptr[row], end = row_ptr[row + 1];
    f32x4 a0 = 0.0f, a1 = 0.0f, a2 = 0.0f, a3 = 0.0f;
    int e = beg;
    for (; e + 16 <= end; e += 16) {           // 16 gathers in flight
        int j0 = col[e+0],  j1 = col[e+1],  j2 = col[e+2],  j3 = col[e+3];
        int j4 = col[e+4],  j5 = col[e+5],  j6 = col[e+6],  j7 = col[e+7];
        int j8 = col[e+8],  j9 = col[e+9],  jA = col[e+10], jB = col[e+11];
        int jC = col[e+12], jD = col[e+13], jE = col[e+14], jF = col[e+15];
        u16x4 h0 = Hs4[j0*64+lane], h1 = Hs4[j1*64+lane];
        u16x4 h2 = Hs4[j2*64+lane], h3 = Hs4[j3*64+lane];
        u16x4 h4 = Hs4[j4*64+lane], h5 = Hs4[j5*64+lane];
        u16x4 h6 = Hs4[j6*64+lane], h7 = Hs4[j7*64+lane];
        u16x4 h8 = Hs4[j8*64+lane], h9 = Hs4[j9*64+lane];
        u16x4 hA = Hs4[jA*64+lane], hB = Hs4[jB*64+lane];
        u16x4 hC = Hs4[jC*64+lane], hD = Hs4[jD*64+lane];
        u16x4 hE = Hs4[jE*64+lane], hF = Hs4[jF*64+lane];
        ACC(a0, h0) ACC(a1, h1) ACC(a2, h2) ACC(a3, h3)
        ACC(a0, h4) ACC(a1, h5) ACC(a2, h6) ACC(a3, h7)
        ACC(a0, h8) ACC(a1, h9) ACC(a2, hA) ACC(a3, hB)
        ACC(a0, hC) ACC(a1, hD) ACC(a2, hE) ACC(a3, hF)
    }
    for (; e + 8 <= end; e += 8) {
        int j0 = col[e+0], j1 = col[e+1], j2 = col[e+2], j3 = col[e+3];
        int j4 = col[e+4], j5 = col[e+5], j6 = col[e+6], j7 = col[e+7];
        u16x4 h0 = Hs4[j0*64+lane], h1 = Hs4[j1*64+lane];
        u16x4 h2 = Hs4[j2*64+lane], h3 = Hs4[j3*64+lane];
        u16x4 h4 = Hs4[j4*64+lane], h5 = Hs4[j5*64+lane];
        u16x4 h6 = Hs4[j6*64+lane], h7 = Hs4[j7*64+lane];
        ACC(a0, h0) ACC(a1, h1) ACC(a2, h2) ACC(a3, h3)
        ACC(a0, h4) ACC(a1, h5) ACC(a2, h6) ACC(a3, h7)
    }
    for (; e + 4 <= end; e += 4) {
        int j0 = col[e+0], j1 = col[e+1], j2 = col[e+2], j3 = col[e+3];
        u16x4 h0 = Hs4[j0*64+lane], h1 = Hs4[j1*64+lane];
        u16x4 h2 = Hs4[j2*64+lane], h3 = Hs4[j3*64+lane];
        ACC(a0, h0) ACC(a1, h1) ACC(a2, h2) ACC(a3, h3)
    }
    for (; e < end; ++e) {
        int j = col[e];
        u16x4 h = Hs4[j*64+lane];
        ACC(a0, h)
    }
    // self loop: H/deg = Hs * dinv  =>  PH = dinv[row] * (sum + Hs_row)
    u16x4 hr = Hs4[row*64+lane];
    ACC(a2, hr)
    f32x4 acc = (a0 + a1) + (a2 + a3);
    float di = dinv[row];
    f32x4 h0v = ((const f32x4*)H0)[row * 64 + lane];
    f32x4 init = (1.0f - alpha) * (di * acc) + alpha * h0v;
    u16x4 o;
    o[0] = f2bf(init[0]); o[1] = f2bf(init[1]);
    o[2] = f2bf(init[2]); o[3] = f2bf(init[3]);
    ((u16x4*)irb)[row * 64 + lane] = o;
}

// ---- GEMM: out = (1-beta)*irb + beta*(irb @ W), bf16 MFMA 16x16x32 --------
// 4 waves/block; block tile 64 rows x 256 cols (A read once);
// wave w owns cols [w*64, w*64+64); K = 256 in 8 steps.

__global__ __launch_bounds__(256) void gemm_kernel(
        const unsigned short* __restrict__ irb, const unsigned short* __restrict__ Wt,
        float* __restrict__ out, const float* __restrict__ lamda_p,
        const int* __restrict__ l_p, int M) {
    int w = threadIdx.x >> 6;
    int mr = blockIdx.x * 64;
    int nc = w * 64;
    int lane = threadIdx.x & 63;
    int lo = lane & 15, hi = lane >> 4;
    float beta = logf(lamda_p[0] / (float)l_p[0] + 1.0f);
    float ob = 1.0f - beta;

    f32x4 acc[4][4] = {};
    for (int kk = 0; kk < 8; ++kk) {
        int kb = kk * 32 + hi * 8;
        short8 a[4], b[4];
        for (int am = 0; am < 4; ++am) {
            int row = mr + am * 16 + lo;
            a[am] = (row < M) ? *(const short8*)(irb + (size_t)row * F_DIM + kb)
                              : (short8)0;
        }
        for (int bn = 0; bn < 4; ++bn) {
            int cb = nc + bn * 16 + lo;
            b[bn] = *(const short8*)(Wt + cb * F_DIM + kb);
        }
        for (int am = 0; am < 4; ++am)
            for (int bn = 0; bn < 4; ++bn)
                acc[am][bn] = __builtin_amdgcn_mfma_f32_16x16x32_bf16(
                    a[am], b[bn], acc[am][bn], 0, 0, 0);
    }

    // C/D layout: col = lane&15, row = (lane>>4)*4 + reg   [m89-verified]
    for (int am = 0; am < 4; ++am) {
        int rbase = mr + am * 16 + hi * 4;
        for (int r = 0; r < 4; ++r) {
            int row = rbase + r;
            if (row >= M) continue;
            for (int bn = 0; bn < 4; ++bn) {
                int c2 = nc + bn * 16 + lo;
                size_t idx = (size_t)row * F_DIM + c2;
                out[idx] = ob * bf2f(irb[idx]) + beta * acc[am][bn][r];
            }
        }
    }
}

// ---- launch ---------------------------------------------------------------

extern "C" void kernel_launch(void* const* d_in, const int* in_sizes, int n_in,
                              void* d_out, int out_size, void* d_ws, size_t ws_size,
                              hipStream_t stream) {
    const float* H     = (const float*)d_in[0];
    const int*   ei    = (const int*)d_in[1];
    const float* H0    = (const float*)d_in[2];
    const float* W     = (const float*)d_in[3];
    const float* lamda = (const float*)d_in[4];
    const float* alpha = (const float*)d_in[5];
    const int*   lp    = (const int*)d_in[6];

    int n = in_sizes[0] / F_DIM;
    int E = in_sizes[1] / 2;
    const int* src = ei;
    const int* dst = ei + E;
    float* out = (float*)d_out;

    int wpc = (n + 1) / 2;                 // packed words per chunk (25000)
    int whalf = (wpc + 1) / 2;             // words in half 0 (12500)
    int nchunk = (E + CHUNK - 1) / CHUNK;  // 80
    int nb = (n + 256) / 256;              // scan blocks covering 0..n (196)

    char* ws = (char*)d_ws;
    size_t off = 0;
    auto alloc = [&](size_t bytes) -> void* {
        void* p = ws + off;
        off += (bytes + 255) & ~(size_t)255;
        return p;
    };
    unsigned* histS = (unsigned*)alloc((size_t)nchunk * wpc * 4);     // 8 MB
    unsigned* histD = (unsigned*)alloc((size_t)nchunk * wpc * 4);     // 8 MB
    unsigned* baseL = (unsigned*)alloc((size_t)nchunk * 2 * wpc * 4); // 16 MB
    unsigned short* lrank = (unsigned short*)alloc((size_t)E * 2);
    int* cnt     = (int*)alloc((size_t)n * 4);
    int* row_ptr = (int*)alloc(((size_t)n + 1) * 4);
    int* blksum  = (int*)alloc((size_t)nb * 4);
    int* blkoff  = (int*)alloc((size_t)nb * 4);
    float* dinv  = (float*)alloc((size_t)n * 4);
    int* colb    = (int*)alloc((size_t)E * 4);
    unsigned short* Wt  = (unsigned short*)alloc((size_t)F_DIM * F_DIM * 2);
    unsigned short* Hs  = (unsigned short*)alloc((size_t)n * F_DIM * 2);
    unsigned short* irb = (unsigned short*)alloc(((size_t)n + 64) * F_DIM * 2);

    hist_kernel<<<nchunk * 4, 1024, 0, stream>>>(src, dst, histS, histD, lrank,
                                                 E, wpc, whalf);
    int wgrid = (wpc + 255) / 256;
    sumbase_kernel<<<wgrid, 256, 0, stream>>>(histS, histD, cnt, dinv, baseL,
                                              wpc, nchunk, n);
    blksum_kernel<<<nb, 256, 0, stream>>>(cnt, blksum, n);
    blkscan_kernel<<<1, 256, 0, stream>>>(blksum, blkoff, nb);
    rowptr_kernel<<<nb, 256, 0, stream>>>(cnt, blkoff, row_ptr, n);
    fill_kernel<<<(E + 255) / 256, 256, 0, stream>>>(src, dst, row_ptr, baseL,
                                                     lrank, colb, E, wpc);
    int total4 = n * 64;
    int hswt_items = total4 + F_DIM * F_DIM;   // Hs vec4 items + Wt scalars
    hswt_kernel<<<(hswt_items + 255) / 256, 256, 0, stream>>>(H, dinv, Hs, W, Wt,
                                                              total4);
    gather_kernel<<<(n + 3) / 4, 256, 0, stream>>>(Hs, H0, row_ptr, colb, dinv,
                                                   alpha, irb, n);
    int mtiles = (n + 63) / 64;
    gemm_kernel<<<mtiles, 256, 0, stream>>>(irb, Wt, out, lamda, lp, n);
}

// Round 10
// 180.821 us; speedup vs baseline: 2.0861x; 1.0511x over previous
//
#include <hip/hip_runtime.h>
#include <math.h>

// GCNII graph convolution, N=50000, F=256, E=800000, f32 in/out.
// R10: revert to bf16 gather payload (fp8 failed absmax 0.046 > 0.0356).
//      Identity folded into W: out = init @ ((1-beta)I + beta*W) -> gemm is
//      pure MFMA+store (no irb re-read). blksum merged into sumbase.
//      Gather: 8-deep unroll (best known: ~70us, L3-fabric-bound).

#define F_DIM 256
#define CHUNK 10000

typedef __attribute__((ext_vector_type(4))) float f32x4;
typedef __attribute__((ext_vector_type(8))) short short8;
typedef __attribute__((ext_vector_type(4))) unsigned short u16x4;

static __device__ __forceinline__ unsigned short f2bf(float f) {
    unsigned int u = __float_as_uint(f);
    u += 0x7fffu + ((u >> 16) & 1u);
    return (unsigned short)(u >> 16);
}
static __device__ __forceinline__ float bf2f(unsigned short u) {
    return __uint_as_float((unsigned int)u << 16);
}

// ---- histogram: block = (chunk c, half h, which). u16-packed LDS counts ----

__global__ __launch_bounds__(1024) void hist_kernel(
        const int* __restrict__ src, const int* __restrict__ dst,
        unsigned* __restrict__ histS, unsigned* __restrict__ histD,
        unsigned short* __restrict__ lrank, int E, int wpc, int whalf) {
    __shared__ unsigned hist[12544];
    int b = blockIdx.x;
    int which = b & 1, h = (b >> 1) & 1, c = b >> 2;
    int tid = threadIdx.x;
    int w0 = h * whalf;
    int hcount = h ? (wpc - whalf) : whalf;
    int e0 = c * CHUNK;
    int e1 = e0 + CHUNK < E ? e0 + CHUNK : E;
    const int* eptr = which ? dst : src;
    unsigned* outh = which ? histD : histS;

    for (int w = tid; w < hcount; w += 1024) hist[w] = 0;
    __syncthreads();
    for (int e = e0 + tid; e < e1; e += 1024) {
        int s = eptr[e];
        int wl = (s >> 1) - w0;
        if ((unsigned)wl < (unsigned)hcount) {
            int sh = (s & 1) * 16;
            unsigned old = atomicAdd(&hist[wl], 1u << sh);
            if (!which) lrank[e] = (unsigned short)((old >> sh) & 0xffffu);
        }
    }
    __syncthreads();
    for (int w = tid; w < hcount; w += 1024)
        outh[(size_t)c * wpc + w0 + w] = hist[w];
}

// ---- histS/histD pass: cnt, dinv, per-chunk local bases, 256-node sums ----
// Block covers 512 nodes -> exactly 2 blksum entries (threads 0-127 / 128-255).

__global__ __launch_bounds__(256) void sumbase_kernel(
        const unsigned* __restrict__ histS, const unsigned* __restrict__ histD,
        int* __restrict__ cnt, float* __restrict__ dinv,
        unsigned* __restrict__ baseL, int* __restrict__ blksum,
        int wpc, int nchunk, int n) {
    int tid = threadIdx.x;
    int w = blockIdx.x * 256 + tid;
    size_t stride2 = (size_t)2 * wpc;
    unsigned slo = 0, shi = 0, dlo = 0, dhi = 0;
    if (w < wpc) {
        for (int c = 0; c < nchunk; ++c) {
            unsigned vs = histS[(size_t)c * wpc + w];
            unsigned vd = histD[(size_t)c * wpc + w];
            baseL[c * stride2 + 2 * w]     = slo;
            baseL[c * stride2 + 2 * w + 1] = shi;
            slo += vs & 0xffffu; shi += vs >> 16;
            dlo += vd & 0xffffu; dhi += vd >> 16;
        }
        int i0 = 2 * w, i1 = 2 * w + 1;
        cnt[i0] = (int)slo;
        dinv[i0] = rsqrtf((float)dlo + 1.0f);
        if (i1 < n) {
            cnt[i1] = (int)shi;
            dinv[i1] = rsqrtf((float)dhi + 1.0f);
        }
    }
    // per-256-node sums for the hierarchical scan
    int contrib = 0;
    if (w < wpc) {
        contrib = (int)slo;
        if (2 * w + 1 < n) contrib += (int)shi;
    }
    int lane = tid & 63, wid = tid >> 6;
    int v = contrib;
    for (int off = 32; off > 0; off >>= 1) v += __shfl_down(v, off, 64);
    __shared__ int ws4[4];
    if (lane == 0) ws4[wid] = v;
    __syncthreads();
    if (tid == 0)   blksum[2 * blockIdx.x]     = ws4[0] + ws4[1];
    if (tid == 128) blksum[2 * blockIdx.x + 1] = ws4[2] + ws4[3];
}

// ---- hierarchical scan over cnt -> row_ptr --------------------------------

__global__ __launch_bounds__(256) void blkscan_kernel(const int* __restrict__ blksum,
                                                      int* __restrict__ blkoff, int nb) {
    int tid = threadIdx.x;
    int v = (tid < nb) ? blksum[tid] : 0;
    int s = v;
    int lane = tid & 63, w = tid >> 6;
    for (int off = 1; off < 64; off <<= 1) {
        int t = __shfl_up(v, off, 64);
        if (lane >= off) v += t;
    }
    __shared__ int ws[4];
    if (lane == 63) ws[w] = v;
    __syncthreads();
    if (tid == 0) {
        int run = 0;
        for (int i = 0; i < 4; ++i) { int t = ws[i]; ws[i] = run; run += t; }
    }
    __syncthreads();
    if (tid < nb) blkoff[tid] = ws[w] + v - s;   // exclusive
}

__global__ __launch_bounds__(256) void rowptr_kernel(const int* __restrict__ cnt,
                                                     const int* __restrict__ blkoff,
                                                     int* __restrict__ row_ptr, int n) {
    int i = blockIdx.x * 256 + threadIdx.x;
    int tid = threadIdx.x;
    int s = (i < n) ? cnt[i] : 0;
    int v = s;
    int lane = tid & 63, w = tid >> 6;
    for (int off = 1; off < 64; off <<= 1) {
        int t = __shfl_up(v, off, 64);
        if (lane >= off) v += t;
    }
    __shared__ int ws[4];
    if (lane == 63) ws[w] = v;
    __syncthreads();
    if (tid == 0) {
        int run = 0;
        for (int k = 0; k < 4; ++k) { int t = ws[k]; ws[k] = run; run += t; }
    }
    __syncthreads();
    if (i <= n) row_ptr[i] = blkoff[blockIdx.x] + ws[w] + v - s;
}

// ---- atomic-free fill: pos = row_ptr[s] + baseL[c][s] + lrank[e] ----------

__global__ __launch_bounds__(256) void fill_kernel(
        const int* __restrict__ src, const int* __restrict__ dst,
        const int* __restrict__ row_ptr, const unsigned* __restrict__ baseL,
        const unsigned short* __restrict__ lrank,
        int* __restrict__ col, int E, int wpc) {
    int e = blockIdx.x * 256 + threadIdx.x;
    if (e < E) {
        int c = e / CHUNK;
        int s = src[e];
        unsigned pos = (unsigned)row_ptr[s] + baseL[(size_t)c * (2 * wpc) + s]
                     + lrank[e];
        col[pos] = dst[e];
    }
}

// ---- Hs = bf16(H * dinv[row])  +  Wt' = bf16(beta*W^T + (1-beta)I) --------

__global__ __launch_bounds__(256) void hswt_kernel(const float* __restrict__ H,
                                                   const float* __restrict__ dinv,
                                                   unsigned short* __restrict__ Hs,
                                                   const float* __restrict__ W,
                                                   unsigned short* __restrict__ Wt,
                                                   const float* __restrict__ lamda_p,
                                                   const int* __restrict__ l_p,
                                                   int total4) {
    int i = blockIdx.x * 256 + threadIdx.x;   // index in f32x4 / u16x4 units
    if (i < total4) {
        int row = i >> 6;                      // 64 x f32x4 per row
        float d = dinv[row];
        f32x4 x = ((const f32x4*)H)[i];
        u16x4 o;
        o[0] = f2bf(x[0] * d); o[1] = f2bf(x[1] * d);
        o[2] = f2bf(x[2] * d); o[3] = f2bf(x[3] * d);
        ((u16x4*)Hs)[i] = o;
    } else {
        int t = i - total4;                    // 0 .. 65535 -> Wt' build
        if (t < F_DIM * F_DIM) {
            float beta = logf(lamda_p[0] / (float)l_p[0] + 1.0f);
            int nn = t >> 8, kk = t & 255;
            float v = beta * W[kk * F_DIM + nn];
            if (kk == nn) v += 1.0f - beta;
            Wt[nn * F_DIM + kk] = f2bf(v);
        }
    }
}

// ---- gather: one wave per row, 512B bf16 loads, 8-deep edge unroll --------

#define ACC(A, h) { A[0] += bf2f(h[0]); A[1] += bf2f(h[1]); \
                    A[2] += bf2f(h[2]); A[3] += bf2f(h[3]); }

__global__ __launch_bounds__(256) void gather_kernel(
        const unsigned short* __restrict__ Hs, const float* __restrict__ H0,
        const int* __restrict__ row_ptr, const int* __restrict__ col,
        const float* __restrict__ dinv, const float* __restrict__ alpha_p,
        unsigned short* __restrict__ irb, int n) {
    int wave = threadIdx.x >> 6;
    int lane = threadIdx.x & 63;
    int row = blockIdx.x * 4 + wave;
    if (row >= n) return;
    float alpha = alpha_p[0];
    const u16x4* Hs4 = (const u16x4*)Hs;

    int beg = row_ptr[row], end = row_ptr[row + 1];
    f32x4 a0 = 0.0f, a1 = 0.0f, a2 = 0.0f, a3 = 0.0f;
    int e = beg;
    for (; e + 8 <= end; e += 8) {             // 8 gathers in flight
        int j0 = col[e+0], j1 = col[e+1], j2 = col[e+2], j3 = col[e+3];
        int j4 = col[e+4], j5 = col[e+5], j6 = col[e+6], j7 = col[e+7];
        u16x4 h0 = Hs4[j0*64+lane], h1 = Hs4[j1*64+lane];
        u16x4 h2 = Hs4[j2*64+lane], h3 = Hs4[j3*64+lane];
        u16x4 h4 = Hs4[j4*64+lane], h5 = Hs4[j5*64+lane];
        u16x4 h6 = Hs4[j6*64+lane], h7 = Hs4[j7*64+lane];
        ACC(a0, h0) ACC(a1, h1) ACC(a2, h2) ACC(a3, h3)
        ACC(a0, h4) ACC(a1, h5) ACC(a2, h6) ACC(a3, h7)
    }
    for (; e + 4 <= end; e += 4) {
        int j0 = col[e+0], j1 = col[e+1], j2 = col[e+2], j3 = col[e+3];
        u16x4 h0 = Hs4[j0*64+lane], h1 = Hs4[j1*64+lane];
        u16x4 h2 = Hs4[j2*64+lane], h3 = Hs4[j3*64+lane];
        ACC(a0, h0) ACC(a1, h1) ACC(a2, h2) ACC(a3, h3)
    }
    for (; e < end; ++e) {
        int j = col[e];
        u16x4 h = Hs4[j*64+lane];
        ACC(a0, h)
    }
    // self loop: H/deg = Hs * dinv  =>  PH = dinv[row] * (sum + Hs_row)
    u16x4 hr = Hs4[row*64+lane];
    ACC(a2, hr)
    f32x4 acc = (a0 + a1) + (a2 + a3);
    float di = dinv[row];
    f32x4 h0v = ((const f32x4*)H0)[row * 64 + lane];
    f32x4 init = (1.0f - alpha) * (di * acc) + alpha * h0v;
    u16x4 o;
    o[0] = f2bf(init[0]); o[1] = f2bf(init[1]);
    o[2] = f2bf(init[2]); o[3] = f2bf(init[3]);
    ((u16x4*)irb)[row * 64 + lane] = o;
}

// ---- GEMM: out = irb @ Wt' (identity pre-folded), pure MFMA + store -------
// 4 waves/block; block tile 64 rows x 256 cols; wave w owns cols [w*64,+64).

__global__ __launch_bounds__(256) void gemm_kernel(
        const unsigned short* __restrict__ irb, const unsigned short* __restrict__ Wt,
        float* __restrict__ out, int M) {
    int w = threadIdx.x >> 6;
    int mr = blockIdx.x * 64;
    int nc = w * 64;
    int lane = threadIdx.x & 63;
    int lo = lane & 15, hi = lane >> 4;

    f32x4 acc[4][4] = {};
    for (int kk = 0; kk < 8; ++kk) {
        int kb = kk * 32 + hi * 8;
        short8 a[4], b[4];
        for (int am = 0; am < 4; ++am) {
            int row = mr + am * 16 + lo;
            a[am] = (row < M) ? *(const short8*)(irb + (size_t)row * F_DIM + kb)
                              : (short8)0;
        }
        for (int bn = 0; bn < 4; ++bn) {
            int cb = nc + bn * 16 + lo;
            b[bn] = *(const short8*)(Wt + cb * F_DIM + kb);
        }
        for (int am = 0; am < 4; ++am)
            for (int bn = 0; bn < 4; ++bn)
                acc[am][bn] = __builtin_amdgcn_mfma_f32_16x16x32_bf16(
                    a[am], b[bn], acc[am][bn], 0, 0, 0);
    }

    // C/D layout: col = lane&15, row = (lane>>4)*4 + reg   [m89-verified]
    for (int am = 0; am < 4; ++am) {
        int rbase = mr + am * 16 + hi * 4;
        for (int r = 0; r < 4; ++r) {
            int row = rbase + r;
            if (row >= M) continue;
            for (int bn = 0; bn < 4; ++bn) {
                int c2 = nc + bn * 16 + lo;
                out[(size_t)row * F_DIM + c2] = acc[am][bn][r];
            }
        }
    }
}

// ---- launch ---------------------------------------------------------------

extern "C" void kernel_launch(void* const* d_in, const int* in_sizes, int n_in,
                              void* d_out, int out_size, void* d_ws, size_t ws_size,
                              hipStream_t stream) {
    const float* H     = (const float*)d_in[0];
    const int*   ei    = (const int*)d_in[1];
    const float* H0    = (const float*)d_in[2];
    const float* W     = (const float*)d_in[3];
    const float* lamda = (const float*)d_in[4];
    const float* alpha = (const float*)d_in[5];
    const int*   lp    = (const int*)d_in[6];

    int n = in_sizes[0] / F_DIM;
    int E = in_sizes[1] / 2;
    const int* src = ei;
    const int* dst = ei + E;
    float* out = (float*)d_out;

    int wpc = (n + 1) / 2;                 // packed words per chunk (25000)
    int whalf = (wpc + 1) / 2;             // words in half 0 (12500)
    int nchunk = (E + CHUNK - 1) / CHUNK;  // 80
    int nb = (n + 256) / 256;              // scan blocks covering 0..n (196)

    char* ws = (char*)d_ws;
    size_t off = 0;
    auto alloc = [&](size_t bytes) -> void* {
        void* p = ws + off;
        off += (bytes + 255) & ~(size_t)255;
        return p;
    };
    unsigned* histS = (unsigned*)alloc((size_t)nchunk * wpc * 4);     // 8 MB
    unsigned* histD = (unsigned*)alloc((size_t)nchunk * wpc * 4);     // 8 MB
    unsigned* baseL = (unsigned*)alloc((size_t)nchunk * 2 * wpc * 4); // 16 MB
    unsigned short* lrank = (unsigned short*)alloc((size_t)E * 2);
    int* cnt     = (int*)alloc((size_t)n * 4);
    int* row_ptr = (int*)alloc(((size_t)n + 1) * 4);
    int* blksum  = (int*)alloc((size_t)(2 * ((wpc + 255) / 256) + 8) * 4);
    int* blkoff  = (int*)alloc((size_t)nb * 4);
    float* dinv  = (float*)alloc((size_t)n * 4);
    int* colb    = (int*)alloc((size_t)E * 4);
    unsigned short* Wt  = (unsigned short*)alloc((size_t)F_DIM * F_DIM * 2);
    unsigned short* Hs  = (unsigned short*)alloc((size_t)n * F_DIM * 2);
    unsigned short* irb = (unsigned short*)alloc(((size_t)n + 64) * F_DIM * 2);

    hist_kernel<<<nchunk * 4, 1024, 0, stream>>>(src, dst, histS, histD, lrank,
                                                 E, wpc, whalf);
    int wgrid = (wpc + 255) / 256;         // 98 blocks -> 196 blksum entries
    sumbase_kernel<<<wgrid, 256, 0, stream>>>(histS, histD, cnt, dinv, baseL,
                                              blksum, wpc, nchunk, n);
    blkscan_kernel<<<1, 256, 0, stream>>>(blksum, blkoff, nb);
    rowptr_kernel<<<nb, 256, 0, stream>>>(cnt, blkoff, row_ptr, n);
    fill_kernel<<<(E + 255) / 256, 256, 0, stream>>>(src, dst, row_ptr, baseL,
                                                     lrank, colb, E, wpc);
    int total4 = n * 64;
    int hswt_items = total4 + F_DIM * F_DIM;   // Hs vec4 items + Wt scalars
    hswt_kernel<<<(hswt_items + 255) / 256, 256, 0, stream>>>(H, dinv, Hs, W, Wt,
                                                              lamda, lp, total4);
    gather_kernel<<<(n + 3) / 4, 256, 0, stream>>>(Hs, H0, row_ptr, colb, dinv,
                                                   alpha, irb, n);
    int mtiles = (n + 63) / 64;
    gemm_kernel<<<mtiles, 256, 0, stream>>>(irb, Wt, out, n);
}

// Round 11
// 162.126 us; speedup vs baseline: 2.3267x; 1.1153x over previous
//
#include <hip/hip_runtime.h>
#include <math.h>

// GCNII graph convolution, N=50000, F=256, E=800000, f32 in/out.
// R11: support-chain compression. CHUNK=20000 (halve hist/sumbase/baseL
//      traffic); baseL = packed u16 local bases (16->4MB, L2-friendly fill);
//      blkscan folded into rowptr (per-block redundant 196-entry scan);
//      fill+hswt merged. 6 dispatches total. Gather (70us, L2-miss-service
//      floor) and gemm (identity-folded, pure MFMA) unchanged from R10.

#define F_DIM 256
#define CHUNK 20000

typedef __attribute__((ext_vector_type(4))) float f32x4;
typedef __attribute__((ext_vector_type(8))) short short8;
typedef __attribute__((ext_vector_type(4))) unsigned short u16x4;

static __device__ __forceinline__ unsigned short f2bf(float f) {
    unsigned int u = __float_as_uint(f);
    u += 0x7fffu + ((u >> 16) & 1u);
    return (unsigned short)(u >> 16);
}
static __device__ __forceinline__ float bf2f(unsigned short u) {
    return __uint_as_float((unsigned int)u << 16);
}

// ---- histogram: block = (chunk c, half h, which). u16-packed LDS counts ----
// word w covers nodes 2w,2w+1; half h owns words [h*whalf, h*whalf+hcount).
// Counts <= CHUNK=20000 < 65536.

__global__ __launch_bounds__(1024) void hist_kernel(
        const int* __restrict__ src, const int* __restrict__ dst,
        unsigned* __restrict__ histS, unsigned* __restrict__ histD,
        unsigned short* __restrict__ lrank, int E, int wpc, int whalf) {
    __shared__ unsigned hist[12544];
    int b = blockIdx.x;
    int which = b & 1, h = (b >> 1) & 1, c = b >> 2;
    int tid = threadIdx.x;
    int w0 = h * whalf;
    int hcount = h ? (wpc - whalf) : whalf;
    int e0 = c * CHUNK;
    int e1 = e0 + CHUNK < E ? e0 + CHUNK : E;
    const int* eptr = which ? dst : src;
    unsigned* outh = which ? histD : histS;

    for (int w = tid; w < hcount; w += 1024) hist[w] = 0;
    __syncthreads();
    for (int e = e0 + tid; e < e1; e += 1024) {
        int s = eptr[e];
        int wl = (s >> 1) - w0;
        if ((unsigned)wl < (unsigned)hcount) {
            int sh = (s & 1) * 16;
            unsigned old = atomicAdd(&hist[wl], 1u << sh);
            if (!which) lrank[e] = (unsigned short)((old >> sh) & 0xffffu);
        }
    }
    __syncthreads();
    for (int w = tid; w < hcount; w += 1024)
        outh[(size_t)c * wpc + w0 + w] = hist[w];
}

// ---- histS/histD pass: cnt, dinv, u16-packed per-chunk bases, blk sums ----
// Block covers 512 nodes -> 2 blksum entries (threads 0-127 / 128-255).
// baseL[c*wpc + w] = (local base of node 2w) | (local base of node 2w+1)<<16.

__global__ __launch_bounds__(256) void sumbase_kernel(
        const unsigned* __restrict__ histS, const unsigned* __restrict__ histD,
        int* __restrict__ cnt, float* __restrict__ dinv,
        unsigned* __restrict__ baseL, int* __restrict__ blksum,
        int wpc, int nchunk, int n) {
    int tid = threadIdx.x;
    int w = blockIdx.x * 256 + tid;
    unsigned slo = 0, shi = 0, dlo = 0, dhi = 0;
    if (w < wpc) {
        for (int c = 0; c < nchunk; ++c) {
            unsigned vs = histS[(size_t)c * wpc + w];
            unsigned vd = histD[(size_t)c * wpc + w];
            baseL[(size_t)c * wpc + w] = slo | (shi << 16);
            slo += vs & 0xffffu; shi += vs >> 16;
            dlo += vd & 0xffffu; dhi += vd >> 16;
        }
        int i0 = 2 * w, i1 = 2 * w + 1;
        cnt[i0] = (int)slo;
        dinv[i0] = rsqrtf((float)dlo + 1.0f);
        if (i1 < n) {
            cnt[i1] = (int)shi;
            dinv[i1] = rsqrtf((float)dhi + 1.0f);
        }
    }
    // per-256-node sums for the hierarchical scan
    int contrib = 0;
    if (w < wpc) {
        contrib = (int)slo;
        if (2 * w + 1 < n) contrib += (int)shi;
    }
    int lane = tid & 63, wid = tid >> 6;
    int v = contrib;
    for (int off = 32; off > 0; off >>= 1) v += __shfl_down(v, off, 64);
    __shared__ int ws4[4];
    if (lane == 0) ws4[wid] = v;
    __syncthreads();
    if (tid == 0)   blksum[2 * blockIdx.x]     = ws4[0] + ws4[1];
    if (tid == 128) blksum[2 * blockIdx.x + 1] = ws4[2] + ws4[3];
}

// ---- row_ptr: each block self-scans the (<=256) blksum entries, then does
// its local 256-entry scan. blkscan kernel eliminated.

__global__ __launch_bounds__(256) void rowptr_kernel(const int* __restrict__ cnt,
                                                     const int* __restrict__ blksum,
                                                     int* __restrict__ row_ptr,
                                                     int n, int nb) {
    int tid = threadIdx.x;
    int lane = tid & 63, w = tid >> 6;
    // exclusive scan of blksum (nb <= 256 entries)
    int bv = (tid < nb) ? blksum[tid] : 0;
    int bs = bv;
    for (int off = 1; off < 64; off <<= 1) {
        int t = __shfl_up(bv, off, 64);
        if (lane >= off) bv += t;
    }
    __shared__ int wsb[4];
    __shared__ int sbo[256];
    if (lane == 63) wsb[w] = bv;
    __syncthreads();
    if (tid == 0) {
        int run = 0;
        for (int k = 0; k < 4; ++k) { int t = wsb[k]; wsb[k] = run; run += t; }
    }
    __syncthreads();
    sbo[tid] = wsb[w] + bv - bs;
    __syncthreads();
    int blockoff = sbo[blockIdx.x];
    // local exclusive scan of this block's 256 cnt entries
    int i = blockIdx.x * 256 + tid;
    int s = (i < n) ? cnt[i] : 0;
    int v = s;
    for (int off = 1; off < 64; off <<= 1) {
        int t = __shfl_up(v, off, 64);
        if (lane >= off) v += t;
    }
    __shared__ int ws[4];
    if (lane == 63) ws[w] = v;
    __syncthreads();
    if (tid == 0) {
        int run = 0;
        for (int k = 0; k < 4; ++k) { int t = ws[k]; ws[k] = run; run += t; }
    }
    __syncthreads();
    if (i <= n) row_ptr[i] = blockoff + ws[w] + v - s;
}

// ---- merged: fill (atomic-free CSR col) + Hs build + Wt' build ------------

__global__ __launch_bounds__(256) void fillhswt_kernel(
        const int* __restrict__ src, const int* __restrict__ dst,
        const int* __restrict__ row_ptr, const unsigned* __restrict__ baseL,
        const unsigned short* __restrict__ lrank, int* __restrict__ col,
        const float* __restrict__ H, const float* __restrict__ dinv,
        unsigned short* __restrict__ Hs,
        const float* __restrict__ W, unsigned short* __restrict__ Wt,
        const float* __restrict__ lamda_p, const int* __restrict__ l_p,
        int E, int wpc, int nfill, int total4) {
    int bid = blockIdx.x;
    int tid = threadIdx.x;
    if (bid < nfill) {
        int e = bid * 256 + tid;
        if (e < E) {
            int c = e / CHUNK;
            int s = src[e];
            unsigned word = baseL[(size_t)c * wpc + (s >> 1)];
            unsigned lb = (s & 1) ? (word >> 16) : (word & 0xffffu);
            unsigned pos = (unsigned)row_ptr[s] + lb + lrank[e];
            col[pos] = dst[e];
        }
    } else {
        int i = (bid - nfill) * 256 + tid;   // f32x4 / u16x4 units
        if (i < total4) {
            int row = i >> 6;                 // 64 x f32x4 per row
            float d = dinv[row];
            f32x4 x = ((const f32x4*)H)[i];
            u16x4 o;
            o[0] = f2bf(x[0] * d); o[1] = f2bf(x[1] * d);
            o[2] = f2bf(x[2] * d); o[3] = f2bf(x[3] * d);
            ((u16x4*)Hs)[i] = o;
        } else {
            int t = i - total4;               // 0..65535 -> Wt' build
            if (t < F_DIM * F_DIM) {
                float beta = logf(lamda_p[0] / (float)l_p[0] + 1.0f);
                int nn = t >> 8, kk = t & 255;
                float v = beta * W[kk * F_DIM + nn];
                if (kk == nn) v += 1.0f - beta;
                Wt[nn * F_DIM + kk] = f2bf(v);
            }
        }
    }
}

// ---- gather: one wave per row, 512B bf16 loads, 8-deep edge unroll --------

#define ACC(A, h) { A[0] += bf2f(h[0]); A[1] += bf2f(h[1]); \
                    A[2] += bf2f(h[2]); A[3] += bf2f(h[3]); }

__global__ __launch_bounds__(256) void gather_kernel(
        const unsigned short* __restrict__ Hs, const float* __restrict__ H0,
        const int* __restrict__ row_ptr, const int* __restrict__ col,
        const float* __restrict__ dinv, const float* __restrict__ alpha_p,
        unsigned short* __restrict__ irb, int n) {
    int wave = threadIdx.x >> 6;
    int lane = threadIdx.x & 63;
    int row = blockIdx.x * 4 + wave;
    if (row >= n) return;
    float alpha = alpha_p[0];
    const u16x4* Hs4 = (const u16x4*)Hs;

    int beg = row_ptr[row], end = row_ptr[row + 1];
    f32x4 a0 = 0.0f, a1 = 0.0f, a2 = 0.0f, a3 = 0.0f;
    int e = beg;
    for (; e + 8 <= end; e += 8) {             // 8 gathers in flight
        int j0 = col[e+0], j1 = col[e+1], j2 = col[e+2], j3 = col[e+3];
        int j4 = col[e+4], j5 = col[e+5], j6 = col[e+6], j7 = col[e+7];
        u16x4 h0 = Hs4[j0*64+lane], h1 = Hs4[j1*64+lane];
        u16x4 h2 = Hs4[j2*64+lane], h3 = Hs4[j3*64+lane];
        u16x4 h4 = Hs4[j4*64+lane], h5 = Hs4[j5*64+lane];
        u16x4 h6 = Hs4[j6*64+lane], h7 = Hs4[j7*64+lane];
        ACC(a0, h0) ACC(a1, h1) ACC(a2, h2) ACC(a3, h3)
        ACC(a0, h4) ACC(a1, h5) ACC(a2, h6) ACC(a3, h7)
    }
    for (; e + 4 <= end; e += 4) {
        int j0 = col[e+0], j1 = col[e+1], j2 = col[e+2], j3 = col[e+3];
        u16x4 h0 = Hs4[j0*64+lane], h1 = Hs4[j1*64+lane];
        u16x4 h2 = Hs4[j2*64+lane], h3 = Hs4[j3*64+lane];
        ACC(a0, h0) ACC(a1, h1) ACC(a2, h2) ACC(a3, h3)
    }
    for (; e < end; ++e) {
        int j = col[e];
        u16x4 h = Hs4[j*64+lane];
        ACC(a0, h)
    }
    // self loop: H/deg = Hs * dinv  =>  PH = dinv[row] * (sum + Hs_row)
    u16x4 hr = Hs4[row*64+lane];
    ACC(a2, hr)
    f32x4 acc = (a0 + a1) + (a2 + a3);
    float di = dinv[row];
    f32x4 h0v = ((const f32x4*)H0)[row * 64 + lane];
    f32x4 init = (1.0f - alpha) * (di * acc) + alpha * h0v;
    u16x4 o;
    o[0] = f2bf(init[0]); o[1] = f2bf(init[1]);
    o[2] = f2bf(init[2]); o[3] = f2bf(init[3]);
    ((u16x4*)irb)[row * 64 + lane] = o;
}

// ---- GEMM: out = irb @ Wt' (identity pre-folded), pure MFMA + store -------
// 4 waves/block; block tile 64 rows x 256 cols; wave w owns cols [w*64,+64).

__global__ __launch_bounds__(256) void gemm_kernel(
        const unsigned short* __restrict__ irb, const unsigned short* __restrict__ Wt,
        float* __restrict__ out, int M) {
    int w = threadIdx.x >> 6;
    int mr = blockIdx.x * 64;
    int nc = w * 64;
    int lane = threadIdx.x & 63;
    int lo = lane & 15, hi = lane >> 4;

    f32x4 acc[4][4] = {};
    for (int kk = 0; kk < 8; ++kk) {
        int kb = kk * 32 + hi * 8;
        short8 a[4], b[4];
        for (int am = 0; am < 4; ++am) {
            int row = mr + am * 16 + lo;
            a[am] = (row < M) ? *(const short8*)(irb + (size_t)row * F_DIM + kb)
                              : (short8)0;
        }
        for (int bn = 0; bn < 4; ++bn) {
            int cb = nc + bn * 16 + lo;
            b[bn] = *(const short8*)(Wt + cb * F_DIM + kb);
        }
        for (int am = 0; am < 4; ++am)
            for (int bn = 0; bn < 4; ++bn)
                acc[am][bn] = __builtin_amdgcn_mfma_f32_16x16x32_bf16(
                    a[am], b[bn], acc[am][bn], 0, 0, 0);
    }

    // C/D layout: col = lane&15, row = (lane>>4)*4 + reg   [m89-verified]
    for (int am = 0; am < 4; ++am) {
        int rbase = mr + am * 16 + hi * 4;
        for (int r = 0; r < 4; ++r) {
            int row = rbase + r;
            if (row >= M) continue;
            for (int bn = 0; bn < 4; ++bn) {
                int c2 = nc + bn * 16 + lo;
                out[(size_t)row * F_DIM + c2] = acc[am][bn][r];
            }
        }
    }
}

// ---- launch ---------------------------------------------------------------

extern "C" void kernel_launch(void* const* d_in, const int* in_sizes, int n_in,
                              void* d_out, int out_size, void* d_ws, size_t ws_size,
                              hipStream_t stream) {
    const float* H     = (const float*)d_in[0];
    const int*   ei    = (const int*)d_in[1];
    const float* H0    = (const float*)d_in[2];
    const float* W     = (const float*)d_in[3];
    const float* lamda = (const float*)d_in[4];
    const float* alpha = (const float*)d_in[5];
    const int*   lp    = (const int*)d_in[6];

    int n = in_sizes[0] / F_DIM;
    int E = in_sizes[1] / 2;
    const int* src = ei;
    const int* dst = ei + E;
    float* out = (float*)d_out;

    int wpc = (n + 1) / 2;                 // packed words per chunk (25000)
    int whalf = (wpc + 1) / 2;             // words in half 0 (12500)
    int nchunk = (E + CHUNK - 1) / CHUNK;  // 40
    int nb = (n + 256) / 256;              // scan blocks covering 0..n (196)

    char* ws = (char*)d_ws;
    size_t off = 0;
    auto alloc = [&](size_t bytes) -> void* {
        void* p = ws + off;
        off += (bytes + 255) & ~(size_t)255;
        return p;
    };
    unsigned* histS = (unsigned*)alloc((size_t)nchunk * wpc * 4);   // 4 MB
    unsigned* histD = (unsigned*)alloc((size_t)nchunk * wpc * 4);   // 4 MB
    unsigned* baseL = (unsigned*)alloc((size_t)nchunk * wpc * 4);   // 4 MB (u16 pairs)
    unsigned short* lrank = (unsigned short*)alloc((size_t)E * 2);
    int* cnt     = (int*)alloc((size_t)n * 4);
    int* row_ptr = (int*)alloc(((size_t)n + 1) * 4);
    int* blksum  = (int*)alloc((size_t)(nb + 8) * 4);
    float* dinv  = (float*)alloc((size_t)n * 4);
    int* colb    = (int*)alloc((size_t)E * 4);
    unsigned short* Wt  = (unsigned short*)alloc((size_t)F_DIM * F_DIM * 2);
    unsigned short* Hs  = (unsigned short*)alloc((size_t)n * F_DIM * 2);
    unsigned short* irb = (unsigned short*)alloc(((size_t)n + 64) * F_DIM * 2);

    hist_kernel<<<nchunk * 4, 1024, 0, stream>>>(src, dst, histS, histD, lrank,
                                                 E, wpc, whalf);
    int wgrid = (wpc + 255) / 256;         // 98 blocks -> 196 blksum entries
    sumbase_kernel<<<wgrid, 256, 0, stream>>>(histS, histD, cnt, dinv, baseL,
                                              blksum, wpc, nchunk, n);
    rowptr_kernel<<<nb, 256, 0, stream>>>(cnt, blksum, row_ptr, n, nb);
    int nfill = (E + 255) / 256;
    int total4 = n * 64;
    int nhswt = (total4 + F_DIM * F_DIM + 255) / 256;
    fillhswt_kernel<<<nfill + nhswt, 256, 0, stream>>>(
        src, dst, row_ptr, baseL, lrank, colb,
        H, dinv, Hs, W, Wt, lamda, lp, E, wpc, nfill, total4);
    gather_kernel<<<(n + 3) / 4, 256, 0, stream>>>(Hs, H0, row_ptr, colb, dinv,
                                                   alpha, irb, n);
    int mtiles = (n + 63) / 64;
    gemm_kernel<<<mtiles, 256, 0, stream>>>(irb, Wt, out, n);
}